// Round 13
// baseline (376.712 us; speedup 1.0000x reference)
//
#include <hip/hip_runtime.h>

// ---------------- problem constants ----------------
#define gB 2
#define gS 4096
#define gH 32
#define gKVH 8
#define gHID 2048
#define gNC 32            // S / CHK
#define gBS (gB*gS)       // 8192
// D = 64, WIN = 256, CHK = 128, NREP = 4 are hard-coded below.

using bf16x8 = __attribute__((ext_vector_type(8))) short;
using f32x4  = __attribute__((ext_vector_type(4))) float;

__device__ __forceinline__ float bf2f(unsigned short u){
  return __uint_as_float(((unsigned)u) << 16);
}
__device__ __forceinline__ unsigned short f2bf(float f){
  unsigned u = __float_as_uint(f);
  u = (u + 0x7fffu + ((u >> 16) & 1u)) >> 16;   // RNE
  return (unsigned short)u;
}
__device__ __forceinline__ float phi_f(float x){ return x > 0.f ? x + 1.f : __expf(x); } // elu(x)+1

__device__ __forceinline__ void unpack8(uint4 v, unsigned short* o){
  o[0]=(unsigned short)(v.x&0xffffu); o[1]=(unsigned short)(v.x>>16);
  o[2]=(unsigned short)(v.y&0xffffu); o[3]=(unsigned short)(v.y>>16);
  o[4]=(unsigned short)(v.z&0xffffu); o[5]=(unsigned short)(v.z>>16);
  o[6]=(unsigned short)(v.w&0xffffu); o[7]=(unsigned short)(v.w>>16);
}
__device__ __forceinline__ uint4 pack8(const unsigned short* s){
  uint4 v;
  v.x = (unsigned)s[0] | ((unsigned)s[1]<<16);
  v.y = (unsigned)s[2] | ((unsigned)s[3]<<16);
  v.z = (unsigned)s[4] | ((unsigned)s[5]<<16);
  v.w = (unsigned)s[6] | ((unsigned)s[7]<<16);
  return v;
}

// async global->LDS, 16B per lane; LDS dest = wave-uniform base + lane*16
typedef const __attribute__((address_space(1))) void* gas_ptr;
typedef __attribute__((address_space(3))) void* las_ptr;
__device__ __forceinline__ void gload16(const void* g, void* l){
  __builtin_amdgcn_global_load_lds((gas_ptr)g, (las_ptr)l, 16, 0, 0);
}

// ---------------- f32 -> bf16 convert ----------------
__global__ void cvt_kernel(const float* __restrict__ in, unsigned short* __restrict__ out, int n){
  int stride = gridDim.x * blockDim.x;
  for (int i = blockIdx.x*blockDim.x + threadIdx.x; i*4 < n; i += stride){
    float4 v = *(const float4*)(in + (size_t)i*4);
    ushort4 o;
    o.x = f2bf(v.x); o.y = f2bf(v.y); o.z = f2bf(v.z); o.w = f2bf(v.w);
    *(ushort4*)(out + (size_t)i*4) = o;
  }
}

// ---------------- 8-phase 256x256 GEMM (T2+T3+T4+T5): C = A[M,K] * B[N,K]^T ----------------
// 8 waves (2M x 4N), wave 128x64 (acc[8][4]). BK=64, 2 LDS buffers of 64KB = 128 KiB.
// Per tile: 4 phases {ds_read batch | stage 1 half-tile (2 gload16) | setprio 16-MFMA | barrier}.
//   ph0: read A(kk0) x8 + B-lo(2n x 2kk) x4; stage B0(t+1); MFMA (kk0, n0..1)
//   ph1: read A(kk1) x8;                      stage B1(t+1); MFMA (kk1, n0..1)
//   ph2: read B-hi x4;                        stage A0(t+2); MFMA (kk0, n2..3)
//   ph3:                                      stage A1(t+2); MFMA (kk1, n2..3)
// A frags held whole tile (64 VGPR) -> A-region LDS reads end by ph1 -> staging
// A(t+2) into the CURRENT buffer at ph2/ph3 is race-free (reads drained before
// ph1's trailing barrier; stage issues after it). B stages target the other buffer.
// Ledger: stage stream ... A0(t+1)@(t-1).ph2, A1(t+1)@(t-1).ph3, B0(t+1)@t.ph0,
// B1(t+1)@t.ph1, A0(t+2)@t.ph2, A1(t+2)@t.ph3. End-of-tile vmcnt(4) retires
// everything except A0/A1(t+2) -> all of tile t+1 confirmed, 4 loads stay in
// flight. Lead of B1(t+1) = 3 phases (~1200cy >= HBM 900). Final tile: vmcnt(0).
// Swizzle (proven BK=64 pair): src chunk g^(row&7) / read chunk (kk*4+lg)^(row&7).
template<int ROPE>
__global__ __launch_bounds__(512, 2) void gemm8p(const unsigned short* __restrict__ A,
                                                 const unsigned short* __restrict__ Bm,
                                                 const float* __restrict__ cosb,
                                                 const float* __restrict__ sinb,
                                                 unsigned short* __restrict__ q_r,
                                                 unsigned short* __restrict__ k_r,
                                                 unsigned short* __restrict__ vproj,
                                                 float* __restrict__ Cout,
                                                 int Ndim)
{
  const int Kdim = 2048;
  __shared__ unsigned short Sh[2*32768];   // buf: A 256x64 @0 (16384 sh), B 256x64 @16384
  int tid = threadIdx.x, lane = tid & 63, w = tid >> 6, lr = lane & 15, lg = lane >> 4;
  int wm = w >> 2, wn = w & 3;
  int ntn = Ndim >> 8;
  int nwg = gridDim.x;
  int bid = (int)blockIdx.x;
  int swz = (bid & 7) * (nwg >> 3) + (bid >> 3);   // XCD-chunked (nwg % 8 == 0)
  long m0 = (long)(swz / ntn) * 256;
  long n0 = (long)(swz % ntn) * 256;
  const int NT = Kdim >> 6;                // 32

  f32x4 acc[8][4] = {};

  // stage one 128x64 half-tile: unit 0=A0(rows0-127) 1=A1 2=B0 3=B1
  auto stageU = [&](int t, int unit){
    int sb = (t & 1) * 32768;
    int k0 = t << 6;
    const unsigned short* G = (unit < 2) ? A : Bm;
    long r0 = (unit < 2) ? m0 : n0;
    int rowbase = (unit & 1) * 128;
    int regionOff = sb + ((unit < 2) ? 0 : 16384) + rowbase*64;
    #pragma unroll
    for (int i = 0; i < 2; ++i){
      int c = w*64 + lane + i*512;          // 0..1023 chunks of 16B
      int row = rowbase + (c >> 3), g = c & 7;
      int colb = (g ^ (row & 7)) << 4;
      gload16((const char*)G + ((r0 + row) * (long)Kdim + k0) * 2 + colb,
              (void*)&Sh[regionOff + c*8]);
    }
  };

  // prologue: tile0 all units + tile1 A-halves = 6 units (12 loads)
  stageU(0,0); stageU(0,1); stageU(0,2); stageU(0,3);
  stageU(1,0); stageU(1,1);
  asm volatile("s_waitcnt vmcnt(4)" ::: "memory");   // tile 0 confirmed
  __builtin_amdgcn_s_barrier();

  for (int t = 0; t < NT; ++t){
    int sb = (t & 1) * 32768;
    bf16x8 a[8][2], bl[2][2];

    // ---- ph0: A(kk0) + B-lo; stage B0(t+1); MFMA (kk0, n0..1) ----
    #pragma unroll
    for (int mg = 0; mg < 8; ++mg){
      int row = wm*128 + mg*16 + lr;
      a[mg][0] = *(const bf16x8*)&Sh[sb + row*64 + ((lg ^ (row & 7)) << 3)];
    }
    #pragma unroll
    for (int nf = 0; nf < 2; ++nf){
      int row = wn*64 + nf*16 + lr;
      #pragma unroll
      for (int kk = 0; kk < 2; ++kk)
        bl[nf][kk] = *(const bf16x8*)&Sh[sb + 16384 + row*64 + (((kk*4 + lg) ^ (row & 7)) << 3)];
    }
    if (t + 1 < NT) stageU(t+1, 2);
    __builtin_amdgcn_s_setprio(1);
    #pragma unroll
    for (int mg = 0; mg < 8; ++mg)
      #pragma unroll
      for (int nf = 0; nf < 2; ++nf)
        acc[mg][nf] = __builtin_amdgcn_mfma_f32_16x16x32_bf16(a[mg][0], bl[nf][0], acc[mg][nf], 0, 0, 0);
    __builtin_amdgcn_s_setprio(0);
    __builtin_amdgcn_s_barrier();

    // ---- ph1: A(kk1); stage B1(t+1); MFMA (kk1, n0..1) ----
    #pragma unroll
    for (int mg = 0; mg < 8; ++mg){
      int row = wm*128 + mg*16 + lr;
      a[mg][1] = *(const bf16x8*)&Sh[sb + row*64 + (((4 + lg) ^ (row & 7)) << 3)];
    }
    if (t + 1 < NT) stageU(t+1, 3);
    __builtin_amdgcn_s_setprio(1);
    #pragma unroll
    for (int mg = 0; mg < 8; ++mg)
      #pragma unroll
      for (int nf = 0; nf < 2; ++nf)
        acc[mg][nf] = __builtin_amdgcn_mfma_f32_16x16x32_bf16(a[mg][1], bl[nf][1], acc[mg][nf], 0, 0, 0);
    __builtin_amdgcn_s_setprio(0);
    __builtin_amdgcn_s_barrier();

    // ---- ph2: B-hi; stage A0(t+2); MFMA (kk0, n2..3) ----
    #pragma unroll
    for (int nf = 0; nf < 2; ++nf){
      int row = wn*64 + (nf+2)*16 + lr;
      #pragma unroll
      for (int kk = 0; kk < 2; ++kk)
        bl[nf][kk] = *(const bf16x8*)&Sh[sb + 16384 + row*64 + (((kk*4 + lg) ^ (row & 7)) << 3)];
    }
    if (t + 2 < NT) stageU(t+2, 0);
    __builtin_amdgcn_s_setprio(1);
    #pragma unroll
    for (int mg = 0; mg < 8; ++mg)
      #pragma unroll
      for (int nf = 0; nf < 2; ++nf)
        acc[mg][nf+2] = __builtin_amdgcn_mfma_f32_16x16x32_bf16(a[mg][0], bl[nf][0], acc[mg][nf+2], 0, 0, 0);
    __builtin_amdgcn_s_setprio(0);
    __builtin_amdgcn_s_barrier();

    // ---- ph3: stage A1(t+2); MFMA (kk1, n2..3); tile-boundary vmcnt ----
    if (t + 2 < NT) stageU(t+2, 1);
    __builtin_amdgcn_s_setprio(1);
    #pragma unroll
    for (int mg = 0; mg < 8; ++mg)
      #pragma unroll
      for (int nf = 0; nf < 2; ++nf)
        acc[mg][nf+2] = __builtin_amdgcn_mfma_f32_16x16x32_bf16(a[mg][1], bl[nf][1], acc[mg][nf+2], 0, 0, 0);
    __builtin_amdgcn_s_setprio(0);
    if (t + 1 < NT){
      if (t + 1 == NT - 1) asm volatile("s_waitcnt vmcnt(0)" ::: "memory");
      else                 asm volatile("s_waitcnt vmcnt(4)" ::: "memory");
    }
    __builtin_amdgcn_s_barrier();
  }

  // ---- epilogue. C/D layout: col = lane&15, row = 4*(lane>>4) + reg ----
  if (ROPE){
    long colbase = n0 + wn*64;               // 64-aligned; wave section-uniform
    if (colbase < 2048){
      int head = (int)(colbase >> 6);
      #pragma unroll
      for (int m = 0; m < 8; ++m)
        #pragma unroll
        for (int r = 0; r < 4; ++r){
          long srow = m0 + wm*128 + m*16 + 4*lg + r;   // = b*gS + s
          int b = (int)(srow >> 12), s = (int)(srow & 4095);
          const float* cp = cosb + srow*64;
          const float* sp = sinb + srow*64;
          unsigned short* op = q_r + ((size_t)(b*gH + head)*gS + s)*64;
          #pragma unroll
          for (int n = 0; n < 2; ++n){
            int d = n*16 + lr;
            float x1 = acc[m][n][r], x2 = acc[m][n+2][r];
            op[d]      = f2bf(x1*cp[d]    - x2*sp[d]);
            op[d+32]   = f2bf(x2*cp[d+32] + x1*sp[d+32]);
          }
        }
    } else if (colbase < 2560){
      int head = (int)(colbase >> 6) - 32;
      #pragma unroll
      for (int m = 0; m < 8; ++m)
        #pragma unroll
        for (int r = 0; r < 4; ++r){
          long srow = m0 + wm*128 + m*16 + 4*lg + r;
          int b = (int)(srow >> 12), s = (int)(srow & 4095);
          const float* cp = cosb + srow*64;
          const float* sp = sinb + srow*64;
          unsigned short* op = k_r + ((size_t)(b*gKVH + head)*gS + s)*64;
          #pragma unroll
          for (int n = 0; n < 2; ++n){
            int d = n*16 + lr;
            float x1 = acc[m][n][r], x2 = acc[m][n+2][r];
            op[d]      = f2bf(x1*cp[d]    - x2*sp[d]);
            op[d+32]   = f2bf(x2*cp[d+32] + x1*sp[d+32]);
          }
        }
    } else {
      #pragma unroll
      for (int m = 0; m < 8; ++m)
        #pragma unroll
        for (int r = 0; r < 4; ++r){
          long srow = m0 + wm*128 + m*16 + 4*lg + r;
          unsigned short* op = vproj + (size_t)srow*512 + (colbase - 2560);
          #pragma unroll
          for (int n = 0; n < 4; ++n)
            op[n*16 + lr] = f2bf(acc[m][n][r]);
        }
    }
  } else {
    #pragma unroll
    for (int m = 0; m < 8; ++m)
      #pragma unroll
      for (int n = 0; n < 4; ++n)
        #pragma unroll
        for (int r = 0; r < 4; ++r){
          long row = m0 + wm*128 + m*16 + 4*lg + r;
          long col = n0 + wn*64 + n*16 + lr;
          Cout[row*Ndim + col] = acc[m][n][r];
        }
  }
}

// ---------------- 64x64 tile transpose -> d-major (B,KVH,64,S) ----------------
__global__ __launch_bounds__(256) void transpose64(const unsigned short* __restrict__ in,
                                                   unsigned short* __restrict__ out,
                                                   int tokStride, int voff, int mode)
{
  __shared__ unsigned short T[64*72];
  int bid = blockIdx.x;
  int st = bid & 63; int kvh = (bid >> 6) & 7; int b = bid >> 9;
  int s0 = st*64;
  int tid = threadIdx.x;
  const unsigned short* ip;
  size_t tokstr;
  if (mode == 0){ ip = in + ((size_t)(b*gKVH+kvh)*gS + s0)*64;                  tokstr = 64; }
  else          { ip = in + (size_t)(b*gS+s0)*tokStride + voff + kvh*64;        tokstr = tokStride; }
  #pragma unroll
  for (int i = 0; i < 2; ++i){
    int cc = tid + 256*i; int sl = cc >> 3, ch = cc & 7;
    *(uint4*)&T[sl*72 + ch*8] = *(const uint4*)&ip[(size_t)sl*tokstr + ch*8];
  }
  __syncthreads();
  unsigned short* op = out + ((size_t)(b*gKVH+kvh)*64)*gS;
  #pragma unroll
  for (int i = 0; i < 2; ++i){
    int cc = tid + 256*i; int d = cc >> 3, ch = cc & 7;
    unsigned short t[8];
    #pragma unroll
    for (int u = 0; u < 8; ++u) t[u] = T[(ch*8+u)*72 + d];
    *(uint4*)&op[(size_t)d*gS + s0 + ch*8] = pack8(t);
  }
}

// ---------------- local sliding-window attention (v3: no-max softmax) ----------------
__global__ __launch_bounds__(512) void local_attn(const unsigned short* __restrict__ q_r,
                                                  const unsigned short* __restrict__ k_r,
                                                  const unsigned short* __restrict__ vt,
                                                  unsigned short* __restrict__ olocal)
{
  __shared__ unsigned short Qs[128*72];
  __shared__ unsigned short Ks[2][64*72];
  __shared__ unsigned short VTs[2][64*72];
  __shared__ unsigned short Ps[8*16*72];
  int bid = blockIdx.x;
  int qt = bid & 31; int h = (bid >> 5) & 31; int b = bid >> 10;
  int kvh = h >> 2;
  int q0 = qt*128;
  int tid = threadIdx.x, lane = tid & 63, w = tid >> 6, lr = lane & 15, lg = lane >> 4;
  const unsigned short* qp = q_r + ((size_t)(b*gH  +h  )*gS + q0)*64;
  const unsigned short* kp = k_r + ((size_t)(b*gKVH+kvh)*gS)*64;
  const unsigned short* vp = vt  + ((size_t)(b*gKVH+kvh)*64)*gS;   // rows d, stride S

  #pragma unroll
  for (int i = 0; i < 2; ++i){
    int cc = tid + 512*i; int row = cc >> 3, ch = cc & 7;
    *(uint4*)&Qs[row*72 + ch*8] = *(const uint4*)&qp[row*64 + ch*8];
  }

  int kt0 = (q0 >= 256) ? 0 : ((256 - q0) >> 6);
  int krow = tid >> 3, kch = tid & 7;       // 64 rows x 8 chunks = 512 threads
  uint4 kreg, vreg;
  {
    int kb = q0 - 256 + kt0*64;
    kreg = *(const uint4*)&kp[(size_t)(kb+krow)*64 + kch*8];
    vreg = *(const uint4*)&vp[(size_t)krow*gS + kb + kch*8];
    *(uint4*)&Ks[0][krow*72 + kch*8]  = kreg;
    *(uint4*)&VTs[0][krow*72 + kch*8] = vreg;
  }

  float psum[4] = {0.f, 0.f, 0.f, 0.f};
  f32x4 accO[4] = {};
  int wq = w*16;

  for (int kt = kt0; kt < 6; ++kt){
    int cur = (kt - kt0) & 1;
    __syncthreads();
    bool more = (kt + 1 < 6);
    if (more){
      int kb2 = q0 - 256 + (kt+1)*64;
      kreg = *(const uint4*)&kp[(size_t)(kb2+krow)*64 + kch*8];
      vreg = *(const uint4*)&vp[(size_t)krow*gS + kb2 + kch*8];
    }

    f32x4 sc[4] = {};
    #pragma unroll
    for (int kk = 0; kk < 64; kk += 32){
      bf16x8 aq = *(const bf16x8*)&Qs[(wq+lr)*72 + kk + 8*lg];
      #pragma unroll
      for (int f = 0; f < 4; ++f){
        bf16x8 bk = *(const bf16x8*)&Ks[cur][(f*16+lr)*72 + kk + 8*lg];
        sc[f] = __builtin_amdgcn_mfma_f32_16x16x32_bf16(aq, bk, sc[f], 0, 0, 0);
      }
    }
    // no-max softmax accumulation: p = keep ? exp(s/8) : 0
    #pragma unroll
    for (int f = 0; f < 4; ++f)
      #pragma unroll
      for (int r = 0; r < 4; ++r){
        int i = wq + 4*lg + r;               // local query row (0..127)
        int j = kt*64 + f*16 + lr;           // window column (0..383)
        bool keep = (j > i) && (j <= i + 256);
        float e = __expf(sc[f][r] * 0.125f);
        float p = keep ? e : 0.f;
        psum[r] += p;
        Ps[w*1152 + (4*lg + r)*72 + f*16 + lr] = f2bf(p);
      }
    // Ps write->read is same-wave LDS (in-order DS pipe) — no barrier needed.
    #pragma unroll
    for (int kk = 0; kk < 64; kk += 32){
      bf16x8 ap = *(const bf16x8*)&Ps[w*1152 + lr*72 + kk + 8*lg];
      #pragma unroll
      for (int dt = 0; dt < 4; ++dt){
        bf16x8 bv = *(const bf16x8*)&VTs[cur][(dt*16+lr)*72 + kk + 8*lg];
        accO[dt] = __builtin_amdgcn_mfma_f32_16x16x32_bf16(ap, bv, accO[dt], 0, 0, 0);
      }
    }
    if (more){
      *(uint4*)&Ks[cur^1][krow*72 + kch*8]  = kreg;
      *(uint4*)&VTs[cur^1][krow*72 + kch*8] = vreg;
    }
  }
  // single 16-lane-group row-sum reduce
  #pragma unroll
  for (int off = 1; off < 16; off <<= 1)
    #pragma unroll
    for (int r = 0; r < 4; ++r) psum[r] += __shfl_xor(psum[r], off);
  #pragma unroll
  for (int dt = 0; dt < 4; ++dt)
    #pragma unroll
    for (int r = 0; r < 4; ++r){
      int s = q0 + wq + 4*lg + r;
      int d = dt*16 + lr;
      float o = accO[dt][r] / psum[r];
      olocal[((size_t)(b*gS+s)*gH + h)*64 + d] = f2bf(0.5f * o);
    }
}

// ---------------- linear attention pass 1 ----------------
__global__ __launch_bounds__(256) void lin_pass1(const unsigned short* __restrict__ ktr,
                                                 const unsigned short* __restrict__ vt,
                                                 float* __restrict__ kvbuf, float* __restrict__ ksbuf)
{
  __shared__ unsigned short pkT[64*136];
  __shared__ unsigned short vT[64*136];
  int bid = blockIdx.x;
  int c = bid & 31; int kvh = (bid >> 5) & 7; int b = bid >> 8;
  int tid = threadIdx.x, lane = tid & 63, w = tid >> 6, lr = lane & 15, lg = lane >> 4;
  int s0 = c*128;
  const unsigned short* kp = ktr + ((size_t)(b*gKVH+kvh)*64)*gS;
  const unsigned short* vp = vt  + ((size_t)(b*gKVH+kvh)*64)*gS;
  #pragma unroll
  for (int i = 0; i < 4; ++i){
    int cc = tid + 256*i; int d = cc >> 4, ch = cc & 15;
    unsigned short t[8]; unpack8(*(const uint4*)&kp[(size_t)d*gS + s0 + ch*8], t);
    #pragma unroll
    for (int u = 0; u < 8; ++u) t[u] = f2bf(phi_f(bf2f(t[u])));
    *(uint4*)&pkT[d*136 + ch*8] = pack8(t);
    *(uint4*)&vT[d*136 + ch*8]  = *(const uint4*)&vp[(size_t)d*gS + s0 + ch*8];
  }
  __syncthreads();
  f32x4 acc[4] = {};
  #pragma unroll
  for (int kk = 0; kk < 128; kk += 32){
    bf16x8 a = *(const bf16x8*)&pkT[(16*w+lr)*136 + kk + 8*lg];
    #pragma unroll
    for (int et = 0; et < 4; ++et){
      bf16x8 bv = *(const bf16x8*)&vT[(16*et+lr)*136 + kk + 8*lg];
      acc[et] = __builtin_amdgcn_mfma_f32_16x16x32_bf16(a, bv, acc[et], 0, 0, 0);
    }
  }
  size_t base = (size_t)((b*gKVH+kvh)*gNC + c);
  float* kvp = kvbuf + base*4096;
  #pragma unroll
  for (int et = 0; et < 4; ++et)
    #pragma unroll
    for (int r = 0; r < 4; ++r)
      kvp[(16*w + 4*lg + r)*64 + 16*et + lr] = acc[et][r];   // d-major [d][e]
  if (tid < 64){
    float sum = 0.f;
    for (int k = 0; k < 128; ++k) sum += bf2f(pkT[tid*136 + k]);
    ksbuf[base*64 + tid] = sum;
  }
}

// ---------------- linear attention pass 2: exclusive scan; kv transposed to e-major ----------------
__global__ void lin_pass2(const float* __restrict__ kvin, float* __restrict__ kvout,
                          float* __restrict__ ksbuf){
  int t = blockIdx.x*256 + threadIdx.x;
  const int per = 4096 + 64;
  if (t >= gB*gKVH*per) return;
  int bh = t / per; int e = t % per;
  if (e < 4096){
    int d = e >> 6, ecol = e & 63;
    const float* p = kvin  + (size_t)bh*gNC*4096 + e;
    float* q       = kvout + (size_t)bh*gNC*4096 + ecol*64 + d;
    float acc = 0.f;
    for (int cix = 0; cix < gNC; ++cix){ float v = p[(size_t)cix*4096]; q[(size_t)cix*4096] = acc; acc += v; }
  } else {
    float* p = ksbuf + (size_t)bh*gNC*64 + (e - 4096);
    float acc = 0.f;
    for (int cix = 0; cix < gNC; ++cix){ float v = p[cix*64]; p[cix*64] = acc; acc += v; }
  }
}

// ---------------- linear attention pass 3 (+ fused combine: hout = olocal + 0.5*lin) ----------------
__global__ __launch_bounds__(256) void lin_pass3(const unsigned short* __restrict__ q_r,
                                                 const unsigned short* __restrict__ k_r,
                                                 const unsigned short* __restrict__ vt,
                                                 const float* __restrict__ SprevT,
                                                 const float* __restrict__ zprev,
                                                 const unsigned short* __restrict__ olocal,
                                                 unsigned short* __restrict__ hout)
{
  __shared__ unsigned short pq[128*72];
  __shared__ unsigned short pk[64*72];
  __shared__ unsigned short Ph[128*72];
  __shared__ unsigned short vT[64*72];
  __shared__ unsigned short SpT[64*72];
  __shared__ float zp[64];

  int bid = blockIdx.x;
  int c = bid & 31; int h = (bid >> 5) & 31; int b = bid >> 10;
  int kvh = h >> 2;
  int tid = threadIdx.x, lane = tid & 63, w = tid >> 6, lr = lane & 15, lg = lane >> 4;
  int s0 = c*128;
  const unsigned short* qp = q_r + ((size_t)(b*gH  +h  )*gS + s0)*64;
  const unsigned short* kp = k_r + ((size_t)(b*gKVH+kvh)*gS + s0)*64;
  const unsigned short* vp = vt  + ((size_t)(b*gKVH+kvh)*64)*gS;
  const float* Sp  = SprevT + ((size_t)((b*gKVH+kvh)*gNC + c))*4096;
  const float* zpg = zprev  + ((size_t)((b*gKVH+kvh)*gNC + c))*64;

  #pragma unroll
  for (int i = 0; i < 4; ++i){
    int cc = tid + 256*i; int row = cc >> 3, d0 = (cc & 7)*8;
    unsigned short t[8]; unpack8(*(const uint4*)(qp + row*64 + d0), t);
    #pragma unroll
    for (int u = 0; u < 8; ++u) pq[row*72 + d0 + u] = f2bf(phi_f(bf2f(t[u])));
  }
  #pragma unroll
  for (int i = 0; i < 16; ++i){
    int f = tid + 256*i; int e = f >> 6, d = f & 63;
    SpT[e*72 + d] = f2bf(Sp[f]);
  }
  if (tid < 64) zp[tid] = zpg[tid];

  float den[2][4] = {};
  f32x4 accO[2][4] = {};

  for (int kh = 0; kh < 2; ++kh){
    __syncthreads();
    #pragma unroll
    for (int i = 0; i < 2; ++i){
      int cc = tid + 256*i; int kr = cc >> 3, d0 = (cc & 7)*8;
      unsigned short t[8]; unpack8(*(const uint4*)(kp + (kh*64+kr)*64 + d0), t);
      #pragma unroll
      for (int u = 0; u < 8; ++u) pk[kr*72 + d0 + u] = f2bf(phi_f(bf2f(t[u])));
      *(uint4*)&vT[kr*72 + d0] = *(const uint4*)&vp[(size_t)kr*gS + s0 + kh*64 + d0];
    }
    __syncthreads();

    f32x4 sc[2][4] = {};
    #pragma unroll
    for (int kk = 0; kk < 64; kk += 32){
      bf16x8 a[2];
      #pragma unroll
      for (int rt = 0; rt < 2; ++rt) a[rt] = *(const bf16x8*)&pq[(32*w+16*rt+lr)*72 + kk + 8*lg];
      #pragma unroll
      for (int ct = 0; ct < 4; ++ct){
        bf16x8 bk = *(const bf16x8*)&pk[(16*ct+lr)*72 + kk + 8*lg];
        #pragma unroll
        for (int rt = 0; rt < 2; ++rt)
          sc[rt][ct] = __builtin_amdgcn_mfma_f32_16x16x32_bf16(a[rt], bk, sc[rt][ct], 0, 0, 0);
      }
    }
    #pragma unroll
    for (int rt = 0; rt < 2; ++rt)
      #pragma unroll
      for (int ct = 0; ct < 4; ++ct)
        #pragma unroll
        for (int r = 0; r < 4; ++r){
          int qrow = 32*w + 16*rt + 4*lg + r;
          int krow = kh*64 + 16*ct + lr;
          float sv = (krow <= qrow) ? sc[rt][ct][r] : 0.f;
          den[rt][r] += sv;
          Ph[qrow*72 + 16*ct + lr] = f2bf(sv);
        }
    #pragma unroll
    for (int kk = 0; kk < 64; kk += 32){
      bf16x8 ap[2];
      #pragma unroll
      for (int rt = 0; rt < 2; ++rt) ap[rt] = *(const bf16x8*)&Ph[(32*w+16*rt+lr)*72 + kk + 8*lg];
      #pragma unroll
      for (int et = 0; et < 4; ++et){
        bf16x8 bv = *(const bf16x8*)&vT[(16*et+lr)*72 + kk + 8*lg];
        #pragma unroll
        for (int rt = 0; rt < 2; ++rt)
          accO[rt][et] = __builtin_amdgcn_mfma_f32_16x16x32_bf16(ap[rt], bv, accO[rt][et], 0, 0, 0);
      }
    }
  }
  #pragma unroll
  for (int kk = 0; kk < 64; kk += 32){
    bf16x8 a[2];
    #pragma unroll
    for (int rt = 0; rt < 2; ++rt) a[rt] = *(const bf16x8*)&pq[(32*w+16*rt+lr)*72 + kk + 8*lg];
    #pragma unroll
    for (int et = 0; et < 4; ++et){
      bf16x8 bs = *(const bf16x8*)&SpT[(16*et+lr)*72 + kk + 8*lg];
      #pragma unroll
      for (int rt = 0; rt < 2; ++rt)
        accO[rt][et] = __builtin_amdgcn_mfma_f32_16x16x32_bf16(a[rt], bs, accO[rt][et], 0, 0, 0);
    }
  }
  #pragma unroll
  for (int rt = 0; rt < 2; ++rt)
    #pragma unroll
    for (int r = 0; r < 4; ++r){
      int qrow = 32*w + 16*rt + 4*lg + r;
      float part = 0.f;
      #pragma unroll
      for (int u = 0; u < 4; ++u){
        int d = 4*lr + u;
        part += bf2f(pq[qrow*72 + d]) * zp[d];
      }
      den[rt][r] += part;
      #pragma unroll
      for (int off = 1; off < 16; off <<= 1)
        den[rt][r] += __shfl_xor(den[rt][r], off);
    }
  #pragma unroll
  for (int rt = 0; rt < 2; ++rt)
    #pragma unroll
    for (int et = 0; et < 4; ++et)
      #pragma unroll
      for (int r = 0; r < 4; ++r){
        int qrow = 32*w + 16*rt + 4*lg + r;
        int e = 16*et + lr;
        float o = accO[rt][et][r] / (den[rt][r] + 1e-6f);
        int s = s0 + qrow;
        size_t idx = ((size_t)(b*gS+s)*gH + h)*64 + e;
        hout[idx] = f2bf(bf2f(olocal[idx]) + 0.5f * o);
      }
}

// ---------------- host launch ----------------
extern "C" void kernel_launch(void* const* d_in, const int* in_sizes, int n_in,
                              void* d_out, int out_size, void* d_ws, size_t ws_size,
                              hipStream_t stream)
{
  const float* hidden = (const float*)d_in[0];
  const float* cosb   = (const float*)d_in[1];
  const float* sinb   = (const float*)d_in[2];
  const float* Wq     = (const float*)d_in[3];
  const float* Wk     = (const float*)d_in[4];
  const float* Wv     = (const float*)d_in[5];
  const float* Wo     = (const float*)d_in[6];
  float* out = (float*)d_out;

  char* ws = (char*)d_ws;
  size_t off = 0;
  auto alloc = [&](size_t bytes)->void*{
    void* p = ws + off; off += (bytes + 255) & ~(size_t)255; return p;
  };
  unsigned short* hbf    = (unsigned short*)alloc((size_t)gBS*gHID*2);   // hidden bf16; reused as hybrid bf16
  unsigned short* wqkv   = (unsigned short*)alloc((size_t)3072*gHID*2);  // [Wq;Wk;Wv]
  unsigned short* wob    = (unsigned short*)alloc((size_t)gHID*gHID*2);
  unsigned short* vproj  = (unsigned short*)alloc((size_t)gBS*512*2);    // (B,S,KVH*64)
  unsigned short* q_r    = (unsigned short*)alloc((size_t)gBS*gHID*2);   // (B,H,S,64)
  unsigned short* k_r    = (unsigned short*)alloc((size_t)gBS*512*2);    // (B,KVH,S,64)
  unsigned short* ktr    = (unsigned short*)alloc((size_t)gBS*512*2);    // (B,KVH,64,S)
  unsigned short* vt     = (unsigned short*)alloc((size_t)gBS*512*2);    // (B,KVH,64,S)
  unsigned short* olocal = (unsigned short*)alloc((size_t)gBS*gHID*2);
  float* kvbuf           = (float*)alloc((size_t)gB*gKVH*gNC*4096*4);
  float* kvT             = (float*)alloc((size_t)gB*gKVH*gNC*4096*4);
  float* ksbuf           = (float*)alloc((size_t)gB*gKVH*gNC*64*4);

  auto cvt = [&](const float* in, unsigned short* o, int n){
    int nb = (n/4 + 255)/256; if (nb > 4096) nb = 4096;
    cvt_kernel<<<dim3(nb), dim3(256), 0, stream>>>(in, o, n);
  };
  cvt(hidden, hbf, gBS*gHID);
  cvt(Wq, wqkv, gHID*gHID);
  cvt(Wk, wqkv + (size_t)2048*gHID, 512*gHID);
  cvt(Wv, wqkv + (size_t)2560*gHID, 512*gHID);
  cvt(Wo, wob, gHID*gHID);

  // fused QKV projection + RoPE + layout (q_r, k_r, vproj) — 8-phase 256^2
  gemm8p<1><<<dim3(32*12), dim3(512), 0, stream>>>(hbf, wqkv, cosb, sinb,
                                                   q_r, k_r, vproj, nullptr, 3072);

  transpose64<<<dim3(gB*gKVH*64), dim3(256), 0, stream>>>(k_r,   ktr, 64,  0, 0);
  transpose64<<<dim3(gB*gKVH*64), dim3(256), 0, stream>>>(vproj, vt,  512, 0, 1);

  local_attn<<<dim3(gB*gH*32), dim3(512), 0, stream>>>(q_r, k_r, vt, olocal);
  lin_pass1<<<dim3(gB*gKVH*gNC), dim3(256), 0, stream>>>(ktr, vt, kvbuf, ksbuf);
  lin_pass2<<<dim3((gB*gKVH*(4096+64) + 255)/256), dim3(256), 0, stream>>>(kvbuf, kvT, ksbuf);
  lin_pass3<<<dim3(gB*gH*gNC), dim3(256), 0, stream>>>(q_r, k_r, vt, kvT, ksbuf, olocal, hbf);

  // Wo — 8-phase 256^2, f32 out, grid 256 = exact fill
  gemm8p<0><<<dim3(32*8), dim3(512), 0, stream>>>(hbf, wob, nullptr, nullptr,
                                                  nullptr, nullptr, nullptr, out, 2048);
}

// Round 14
// 329.654 us; speedup vs baseline: 1.1427x; 1.1427x over previous
//
#include <hip/hip_runtime.h>

// ---------------- problem constants ----------------
#define gB 2
#define gS 4096
#define gH 32
#define gKVH 8
#define gHID 2048
#define gNC 32            // S / CHK
#define gBS (gB*gS)       // 8192
// D = 64, WIN = 256, CHK = 128, NREP = 4 are hard-coded below.

using bf16x8 = __attribute__((ext_vector_type(8))) short;
using f32x4  = __attribute__((ext_vector_type(4))) float;

__device__ __forceinline__ float bf2f(unsigned short u){
  return __uint_as_float(((unsigned)u) << 16);
}
__device__ __forceinline__ unsigned short f2bf(float f){
  unsigned u = __float_as_uint(f);
  u = (u + 0x7fffu + ((u >> 16) & 1u)) >> 16;   // RNE
  return (unsigned short)u;
}
__device__ __forceinline__ float phi_f(float x){ return x > 0.f ? x + 1.f : __expf(x); } // elu(x)+1

__device__ __forceinline__ void unpack8(uint4 v, unsigned short* o){
  o[0]=(unsigned short)(v.x&0xffffu); o[1]=(unsigned short)(v.x>>16);
  o[2]=(unsigned short)(v.y&0xffffu); o[3]=(unsigned short)(v.y>>16);
  o[4]=(unsigned short)(v.z&0xffffu); o[5]=(unsigned short)(v.z>>16);
  o[6]=(unsigned short)(v.w&0xffffu); o[7]=(unsigned short)(v.w>>16);
}
__device__ __forceinline__ uint4 pack8(const unsigned short* s){
  uint4 v;
  v.x = (unsigned)s[0] | ((unsigned)s[1]<<16);
  v.y = (unsigned)s[2] | ((unsigned)s[3]<<16);
  v.z = (unsigned)s[4] | ((unsigned)s[5]<<16);
  v.w = (unsigned)s[6] | ((unsigned)s[7]<<16);
  return v;
}

// async global->LDS, 16B per lane; LDS dest = wave-uniform base + lane*16
typedef const __attribute__((address_space(1))) void* gas_ptr;
typedef __attribute__((address_space(3))) void* las_ptr;
__device__ __forceinline__ void gload16(const void* g, void* l){
  __builtin_amdgcn_global_load_lds((gas_ptr)g, (las_ptr)l, 16, 0, 0);
}

// ---------------- fused f32 -> bf16 convert (hidden + Wq + Wk + Wv + Wo, 1 launch) ----------------
__global__ void cvt_all(const float* __restrict__ hidden, const float* __restrict__ Wq,
                        const float* __restrict__ Wk, const float* __restrict__ Wv,
                        const float* __restrict__ Wo, unsigned short* __restrict__ hbf,
                        unsigned short* __restrict__ wqkv, unsigned short* __restrict__ wob)
{
  const long HG = (long)gBS*gHID/4;        // 4,194,304 groups of 4 floats
  const long QG = 1048576, KG = 262144, VG = 262144, OG = 1048576;
  const long total = HG + QG + KG + VG + OG;
  long stride = (long)gridDim.x * blockDim.x;
  for (long i = (long)blockIdx.x*blockDim.x + threadIdx.x; i < total; i += stride){
    const float* src; unsigned short* dst; long off;
    if (i < HG)                { src = hidden; dst = hbf;                          off = i; }
    else if (i < HG+QG)        { src = Wq;     dst = wqkv;                         off = i - HG; }
    else if (i < HG+QG+KG)     { src = Wk;     dst = wqkv + (size_t)2048*gHID;     off = i - HG - QG; }
    else if (i < HG+QG+KG+VG)  { src = Wv;     dst = wqkv + (size_t)2560*gHID;     off = i - HG - QG - KG; }
    else                       { src = Wo;     dst = wob;                          off = i - HG - QG - KG - VG; }
    float4 v = *(const float4*)(src + off*4);
    ushort4 o;
    o.x = f2bf(v.x); o.y = f2bf(v.y); o.z = f2bf(v.z); o.w = f2bf(v.w);
    *(ushort4*)(dst + off*4) = o;
  }
}

// ---------------- QKV GEMM 128x256, BK=64, 2-buffer, 1 barrier/K-tile ----------------
// (round-11 proven version: 122-123 us) + fused RoPE/layout epilogue.
__global__ __launch_bounds__(512, 2) void gemm_qkv(const unsigned short* __restrict__ A,
                                                   const unsigned short* __restrict__ Bm,
                                                   const float* __restrict__ cosb,
                                                   const float* __restrict__ sinb,
                                                   unsigned short* __restrict__ q_r,
                                                   unsigned short* __restrict__ k_r,
                                                   unsigned short* __restrict__ vproj)
{
  const int Kdim = 2048;
  __shared__ unsigned short Sh[2*24576];   // buf: A (8192 shorts) + B (16384 shorts)
  int tid = threadIdx.x, lane = tid & 63, w = tid >> 6, lr = lane & 15, lg = lane >> 4;
  int wm = w >> 2, wn = w & 3;
  const int ntn = 12;                      // 3072/256
  int nwg = gridDim.x;
  int bid = (int)blockIdx.x;
  int swz = (bid & 7) * (nwg >> 3) + (bid >> 3);   // XCD-chunked (nwg % 8 == 0)
  long m0 = (long)(swz / ntn) * 128;
  long n0 = (long)(swz % ntn) * 256;
  const int NT = Kdim >> 6;                // 32

  f32x4 acc[4][4] = {};

  auto stage = [&](int t){
    int sbase = (t & 1) * 24576;
    int k0 = t << 6;
    #pragma unroll
    for (int i = 0; i < 2; ++i){           // A: 1024 chunks (128 rows x 8)
      int c = w*64 + lane + i*512;
      int row = c >> 3, g = c & 7;
      int colb = (g ^ (row & 7)) << 4;
      gload16((const char*)A + ((m0 + row) * (long)Kdim + k0) * 2 + colb,
              (void*)&Sh[sbase + (w*64 + i*512)*8]);
    }
    #pragma unroll
    for (int i = 0; i < 4; ++i){           // B: 2048 chunks (256 rows x 8)
      int c = w*64 + lane + i*512;
      int row = c >> 3, g = c & 7;
      int colb = (g ^ (row & 7)) << 4;
      gload16((const char*)Bm + ((n0 + row) * (long)Kdim + k0) * 2 + colb,
              (void*)&Sh[sbase + 8192 + (w*64 + i*512)*8]);
    }
  };

  stage(0);
  for (int t = 0; t < NT; ++t){
    asm volatile("s_waitcnt vmcnt(0)" ::: "memory");
    __builtin_amdgcn_s_barrier();
    if (t + 1 < NT) stage(t + 1);
    int sb = (t & 1) * 24576;
    #pragma unroll
    for (int kk = 0; kk < 2; ++kk){
      bf16x8 af[4], bfr[4];
      #pragma unroll
      for (int m = 0; m < 4; ++m){
        int row = wm*64 + m*16 + lr;
        af[m] = *(const bf16x8*)&Sh[sb + row*64 + (((kk*4 + lg) ^ (row & 7)) << 3)];
      }
      #pragma unroll
      for (int n = 0; n < 4; ++n){
        int row = wn*64 + n*16 + lr;
        bfr[n] = *(const bf16x8*)&Sh[sb + 8192 + row*64 + (((kk*4 + lg) ^ (row & 7)) << 3)];
      }
      __builtin_amdgcn_s_setprio(1);
      #pragma unroll
      for (int m = 0; m < 4; ++m)
        #pragma unroll
        for (int n = 0; n < 4; ++n)
          acc[m][n] = __builtin_amdgcn_mfma_f32_16x16x32_bf16(af[m], bfr[n], acc[m][n], 0, 0, 0);
      __builtin_amdgcn_s_setprio(0);
    }
  }

  // ---- fused epilogue. C/D layout: col = lane&15, row = 4*(lane>>4) + reg ----
  long colbase = n0 + wn*64;                 // 64-aligned; block section-uniform
  if (colbase < 2048){
    int head = (int)(colbase >> 6);
    #pragma unroll
    for (int m = 0; m < 4; ++m)
      #pragma unroll
      for (int r = 0; r < 4; ++r){
        long srow = m0 + wm*64 + m*16 + 4*lg + r;   // = b*gS + s
        int b = (int)(srow >> 12), s = (int)(srow & 4095);
        const float* cp = cosb + srow*64;
        const float* sp = sinb + srow*64;
        unsigned short* op = q_r + ((size_t)(b*gH + head)*gS + s)*64;
        #pragma unroll
        for (int n = 0; n < 2; ++n){
          int d = n*16 + lr;
          float x1 = acc[m][n][r], x2 = acc[m][n+2][r];
          op[d]      = f2bf(x1*cp[d]    - x2*sp[d]);
          op[d+32]   = f2bf(x2*cp[d+32] + x1*sp[d+32]);
        }
      }
  } else if (colbase < 2560){
    int head = (int)(colbase >> 6) - 32;
    #pragma unroll
    for (int m = 0; m < 4; ++m)
      #pragma unroll
      for (int r = 0; r < 4; ++r){
        long srow = m0 + wm*64 + m*16 + 4*lg + r;
        int b = (int)(srow >> 12), s = (int)(srow & 4095);
        const float* cp = cosb + srow*64;
        const float* sp = sinb + srow*64;
        unsigned short* op = k_r + ((size_t)(b*gKVH + head)*gS + s)*64;
        #pragma unroll
        for (int n = 0; n < 2; ++n){
          int d = n*16 + lr;
          float x1 = acc[m][n][r], x2 = acc[m][n+2][r];
          op[d]      = f2bf(x1*cp[d]    - x2*sp[d]);
          op[d+32]   = f2bf(x2*cp[d+32] + x1*sp[d+32]);
        }
      }
  } else {
    #pragma unroll
    for (int m = 0; m < 4; ++m)
      #pragma unroll
      for (int r = 0; r < 4; ++r){
        long srow = m0 + wm*64 + m*16 + 4*lg + r;
        unsigned short* op = vproj + (size_t)srow*512 + (colbase - 2560);
        #pragma unroll
        for (int n = 0; n < 4; ++n)
          op[n*16 + lr] = f2bf(acc[m][n][r]);
      }
  }
}

// ---------------- GEMM 256x256, BK=64, 2-buffer, 1 barrier/K-tile (Wo, round-11) ----------------
template<int OUT_BF16>
__global__ __launch_bounds__(512, 2) void gemm256(const unsigned short* __restrict__ A,
                                                  const unsigned short* __restrict__ Bm,
                                                  void* __restrict__ Cout,
                                                  int Mdim, int Ndim, int Kdim)
{
  __shared__ unsigned short Sh[2*32768];   // buf: A (16384 shorts) + B (16384 shorts)
  int tid = threadIdx.x, lane = tid & 63, w = tid >> 6, lr = lane & 15, lg = lane >> 4;
  int wm = w >> 2, wn = w & 3;
  int ntn = Ndim >> 8;
  int nwg = gridDim.x;
  int bid = (int)blockIdx.x;
  int swz = (bid & 7) * (nwg >> 3) + (bid >> 3);   // XCD-chunked (nwg % 8 == 0)
  long m0 = (long)(swz / ntn) * 256;
  long n0 = (long)(swz % ntn) * 256;
  int NT = Kdim >> 6;

  f32x4 acc[8][4] = {};

  auto stage = [&](int t){
    int sbase = (t & 1) * 32768;
    int k0 = t << 6;
    #pragma unroll
    for (int i = 0; i < 4; ++i){           // A and B: 2048 chunks each (256 rows x 8)
      int c = w*64 + lane + i*512;
      int row = c >> 3, g = c & 7;
      int colb = (g ^ (row & 7)) << 4;
      gload16((const char*)A + ((m0 + row) * (long)Kdim + k0) * 2 + colb,
              (void*)&Sh[sbase + (w*64 + i*512)*8]);
      gload16((const char*)Bm + ((n0 + row) * (long)Kdim + k0) * 2 + colb,
              (void*)&Sh[sbase + 16384 + (w*64 + i*512)*8]);
    }
  };

  stage(0);
  for (int t = 0; t < NT; ++t){
    asm volatile("s_waitcnt vmcnt(0)" ::: "memory");
    __builtin_amdgcn_s_barrier();
    if (t + 1 < NT) stage(t + 1);
    int sb = (t & 1) * 32768;
    #pragma unroll
    for (int kk = 0; kk < 2; ++kk){
      bf16x8 af[8], bfr[4];
      #pragma unroll
      for (int m = 0; m < 8; ++m){
        int row = wm*128 + m*16 + lr;
        af[m] = *(const bf16x8*)&Sh[sb + row*64 + (((kk*4 + lg) ^ (row & 7)) << 3)];
      }
      #pragma unroll
      for (int n = 0; n < 4; ++n){
        int row = wn*64 + n*16 + lr;
        bfr[n] = *(const bf16x8*)&Sh[sb + 16384 + row*64 + (((kk*4 + lg) ^ (row & 7)) << 3)];
      }
      __builtin_amdgcn_s_setprio(1);
      #pragma unroll
      for (int m = 0; m < 8; ++m)
        #pragma unroll
        for (int n = 0; n < 4; ++n)
          acc[m][n] = __builtin_amdgcn_mfma_f32_16x16x32_bf16(af[m], bfr[n], acc[m][n], 0, 0, 0);
      __builtin_amdgcn_s_setprio(0);
    }
  }

  // epilogue: C/D layout col = lane&15, row = 4*(lane>>4) + reg
  #pragma unroll
  for (int m = 0; m < 8; ++m)
    #pragma unroll
    for (int n = 0; n < 4; ++n)
      #pragma unroll
      for (int r = 0; r < 4; ++r){
        long row = m0 + wm*128 + m*16 + 4*lg + r;
        long col = n0 + wn*64 + n*16 + lr;
        float v = acc[m][n][r];
        if (OUT_BF16) ((unsigned short*)Cout)[row*Ndim + col] = f2bf(v);
        else          ((float*)Cout)[row*Ndim + col] = v;
      }
}

// ---------------- 64x64 tile transpose -> d-major (B,KVH,64,S) ----------------
__global__ __launch_bounds__(256) void transpose64(const unsigned short* __restrict__ in,
                                                   unsigned short* __restrict__ out,
                                                   int tokStride, int voff, int mode)
{
  __shared__ unsigned short T[64*72];
  int bid = blockIdx.x;
  int st = bid & 63; int kvh = (bid >> 6) & 7; int b = bid >> 9;
  int s0 = st*64;
  int tid = threadIdx.x;
  const unsigned short* ip;
  size_t tokstr;
  if (mode == 0){ ip = in + ((size_t)(b*gKVH+kvh)*gS + s0)*64;                  tokstr = 64; }
  else          { ip = in + (size_t)(b*gS+s0)*tokStride + voff + kvh*64;        tokstr = tokStride; }
  #pragma unroll
  for (int i = 0; i < 2; ++i){
    int cc = tid + 256*i; int sl = cc >> 3, ch = cc & 7;
    *(uint4*)&T[sl*72 + ch*8] = *(const uint4*)&ip[(size_t)sl*tokstr + ch*8];
  }
  __syncthreads();
  unsigned short* op = out + ((size_t)(b*gKVH+kvh)*64)*gS;
  #pragma unroll
  for (int i = 0; i < 2; ++i){
    int cc = tid + 256*i; int d = cc >> 3, ch = cc & 7;
    unsigned short t[8];
    #pragma unroll
    for (int u = 0; u < 8; ++u) t[u] = T[(ch*8+u)*72 + d];
    *(uint4*)&op[(size_t)d*gS + s0 + ch*8] = pack8(t);
  }
}

// ---------------- local sliding-window attention (v3: no-max softmax) ----------------
__global__ __launch_bounds__(512) void local_attn(const unsigned short* __restrict__ q_r,
                                                  const unsigned short* __restrict__ k_r,
                                                  const unsigned short* __restrict__ vt,
                                                  unsigned short* __restrict__ olocal)
{
  __shared__ unsigned short Qs[128*72];
  __shared__ unsigned short Ks[2][64*72];
  __shared__ unsigned short VTs[2][64*72];
  __shared__ unsigned short Ps[8*16*72];
  int bid = blockIdx.x;
  int qt = bid & 31; int h = (bid >> 5) & 31; int b = bid >> 10;
  int kvh = h >> 2;
  int q0 = qt*128;
  int tid = threadIdx.x, lane = tid & 63, w = tid >> 6, lr = lane & 15, lg = lane >> 4;
  const unsigned short* qp = q_r + ((size_t)(b*gH  +h  )*gS + q0)*64;
  const unsigned short* kp = k_r + ((size_t)(b*gKVH+kvh)*gS)*64;
  const unsigned short* vp = vt  + ((size_t)(b*gKVH+kvh)*64)*gS;   // rows d, stride S

  #pragma unroll
  for (int i = 0; i < 2; ++i){
    int cc = tid + 512*i; int row = cc >> 3, ch = cc & 7;
    *(uint4*)&Qs[row*72 + ch*8] = *(const uint4*)&qp[row*64 + ch*8];
  }

  int kt0 = (q0 >= 256) ? 0 : ((256 - q0) >> 6);
  int krow = tid >> 3, kch = tid & 7;       // 64 rows x 8 chunks = 512 threads
  uint4 kreg, vreg;
  {
    int kb = q0 - 256 + kt0*64;
    kreg = *(const uint4*)&kp[(size_t)(kb+krow)*64 + kch*8];
    vreg = *(const uint4*)&vp[(size_t)krow*gS + kb + kch*8];
    *(uint4*)&Ks[0][krow*72 + kch*8]  = kreg;
    *(uint4*)&VTs[0][krow*72 + kch*8] = vreg;
  }

  float psum[4] = {0.f, 0.f, 0.f, 0.f};
  f32x4 accO[4] = {};
  int wq = w*16;

  for (int kt = kt0; kt < 6; ++kt){
    int cur = (kt - kt0) & 1;
    __syncthreads();
    bool more = (kt + 1 < 6);
    if (more){
      int kb2 = q0 - 256 + (kt+1)*64;
      kreg = *(const uint4*)&kp[(size_t)(kb2+krow)*64 + kch*8];
      vreg = *(const uint4*)&vp[(size_t)krow*gS + kb2 + kch*8];
    }

    f32x4 sc[4] = {};
    #pragma unroll
    for (int kk = 0; kk < 64; kk += 32){
      bf16x8 aq = *(const bf16x8*)&Qs[(wq+lr)*72 + kk + 8*lg];
      #pragma unroll
      for (int f = 0; f < 4; ++f){
        bf16x8 bk = *(const bf16x8*)&Ks[cur][(f*16+lr)*72 + kk + 8*lg];
        sc[f] = __builtin_amdgcn_mfma_f32_16x16x32_bf16(aq, bk, sc[f], 0, 0, 0);
      }
    }
    // no-max softmax accumulation: p = keep ? exp(s/8) : 0
    #pragma unroll
    for (int f = 0; f < 4; ++f)
      #pragma unroll
      for (int r = 0; r < 4; ++r){
        int i = wq + 4*lg + r;               // local query row (0..127)
        int j = kt*64 + f*16 + lr;           // window column (0..383)
        bool keep = (j > i) && (j <= i + 256);
        float e = __expf(sc[f][r] * 0.125f);
        float p = keep ? e : 0.f;
        psum[r] += p;
        Ps[w*1152 + (4*lg + r)*72 + f*16 + lr] = f2bf(p);
      }
    // Ps write->read is same-wave LDS (in-order DS pipe) — no barrier needed.
    #pragma unroll
    for (int kk = 0; kk < 64; kk += 32){
      bf16x8 ap = *(const bf16x8*)&Ps[w*1152 + lr*72 + kk + 8*lg];
      #pragma unroll
      for (int dt = 0; dt < 4; ++dt){
        bf16x8 bv = *(const bf16x8*)&VTs[cur][(dt*16+lr)*72 + kk + 8*lg];
        accO[dt] = __builtin_amdgcn_mfma_f32_16x16x32_bf16(ap, bv, accO[dt], 0, 0, 0);
      }
    }
    if (more){
      *(uint4*)&Ks[cur^1][krow*72 + kch*8]  = kreg;
      *(uint4*)&VTs[cur^1][krow*72 + kch*8] = vreg;
    }
  }
  // single 16-lane-group row-sum reduce
  #pragma unroll
  for (int off = 1; off < 16; off <<= 1)
    #pragma unroll
    for (int r = 0; r < 4; ++r) psum[r] += __shfl_xor(psum[r], off);
  #pragma unroll
  for (int dt = 0; dt < 4; ++dt)
    #pragma unroll
    for (int r = 0; r < 4; ++r){
      int s = q0 + wq + 4*lg + r;
      int d = dt*16 + lr;
      float o = accO[dt][r] / psum[r];
      olocal[((size_t)(b*gS+s)*gH + h)*64 + d] = f2bf(0.5f * o);
    }
}

// ---------------- linear attention pass 1 ----------------
__global__ __launch_bounds__(256) void lin_pass1(const unsigned short* __restrict__ ktr,
                                                 const unsigned short* __restrict__ vt,
                                                 float* __restrict__ kvbuf, float* __restrict__ ksbuf)
{
  __shared__ unsigned short pkT[64*136];
  __shared__ unsigned short vT[64*136];
  int bid = blockIdx.x;
  int c = bid & 31; int kvh = (bid >> 5) & 7; int b = bid >> 8;
  int tid = threadIdx.x, lane = tid & 63, w = tid >> 6, lr = lane & 15, lg = lane >> 4;
  int s0 = c*128;
  const unsigned short* kp = ktr + ((size_t)(b*gKVH+kvh)*64)*gS;
  const unsigned short* vp = vt  + ((size_t)(b*gKVH+kvh)*64)*gS;
  #pragma unroll
  for (int i = 0; i < 4; ++i){
    int cc = tid + 256*i; int d = cc >> 4, ch = cc & 15;
    unsigned short t[8]; unpack8(*(const uint4*)&kp[(size_t)d*gS + s0 + ch*8], t);
    #pragma unroll
    for (int u = 0; u < 8; ++u) t[u] = f2bf(phi_f(bf2f(t[u])));
    *(uint4*)&pkT[d*136 + ch*8] = pack8(t);
    *(uint4*)&vT[d*136 + ch*8]  = *(const uint4*)&vp[(size_t)d*gS + s0 + ch*8];
  }
  __syncthreads();
  f32x4 acc[4] = {};
  #pragma unroll
  for (int kk = 0; kk < 128; kk += 32){
    bf16x8 a = *(const bf16x8*)&pkT[(16*w+lr)*136 + kk + 8*lg];
    #pragma unroll
    for (int et = 0; et < 4; ++et){
      bf16x8 bv = *(const bf16x8*)&vT[(16*et+lr)*136 + kk + 8*lg];
      acc[et] = __builtin_amdgcn_mfma_f32_16x16x32_bf16(a, bv, acc[et], 0, 0, 0);
    }
  }
  size_t base = (size_t)((b*gKVH+kvh)*gNC + c);
  float* kvp = kvbuf + base*4096;
  #pragma unroll
  for (int et = 0; et < 4; ++et)
    #pragma unroll
    for (int r = 0; r < 4; ++r)
      kvp[(16*w + 4*lg + r)*64 + 16*et + lr] = acc[et][r];   // d-major [d][e]
  if (tid < 64){
    float sum = 0.f;
    for (int k = 0; k < 128; ++k) sum += bf2f(pkT[tid*136 + k]);
    ksbuf[base*64 + tid] = sum;
  }
}

// ---------------- linear attention pass 2: in-place exclusive scan (d-major kept) ----------------
__global__ void lin_pass2(float* __restrict__ kvbuf, float* __restrict__ ksbuf){
  int t = blockIdx.x*256 + threadIdx.x;
  const int per = 4096 + 64;
  if (t >= gB*gKVH*per) return;
  int bh = t / per; int e = t % per;
  if (e < 4096){
    float* p = kvbuf + (size_t)bh*gNC*4096 + e;   // coalesced read AND write
    float acc = 0.f;
    for (int cix = 0; cix < gNC; ++cix){ float v = p[(size_t)cix*4096]; p[(size_t)cix*4096] = acc; acc += v; }
  } else {
    float* p = ksbuf + (size_t)bh*gNC*64 + (e - 4096);
    float acc = 0.f;
    for (int cix = 0; cix < gNC; ++cix){ float v = p[cix*64]; p[cix*64] = acc; acc += v; }
  }
}

// ---------------- linear attention pass 3 (+ fused combine: hout = olocal + 0.5*lin) ----------------
// Sprev is d-major [d][e] (kvbuf after in-place scan).
__global__ __launch_bounds__(256) void lin_pass3(const unsigned short* __restrict__ q_r,
                                                 const unsigned short* __restrict__ k_r,
                                                 const unsigned short* __restrict__ vt,
                                                 const float* __restrict__ Sprev,
                                                 const float* __restrict__ zprev,
                                                 const unsigned short* __restrict__ olocal,
                                                 unsigned short* __restrict__ hout)
{
  __shared__ unsigned short pq[128*72];
  __shared__ unsigned short pk[64*72];
  __shared__ unsigned short Ph[128*72];
  __shared__ unsigned short vT[64*72];
  __shared__ unsigned short SpT[64*72];
  __shared__ float zp[64];

  int bid = blockIdx.x;
  int c = bid & 31; int h = (bid >> 5) & 31; int b = bid >> 10;
  int kvh = h >> 2;
  int tid = threadIdx.x, lane = tid & 63, w = tid >> 6, lr = lane & 15, lg = lane >> 4;
  int s0 = c*128;
  const unsigned short* qp = q_r + ((size_t)(b*gH  +h  )*gS + s0)*64;
  const unsigned short* kp = k_r + ((size_t)(b*gKVH+kvh)*gS + s0)*64;
  const unsigned short* vp = vt  + ((size_t)(b*gKVH+kvh)*64)*gS;
  const float* Sp  = Sprev + ((size_t)((b*gKVH+kvh)*gNC + c))*4096;
  const float* zpg = zprev + ((size_t)((b*gKVH+kvh)*gNC + c))*64;

  #pragma unroll
  for (int i = 0; i < 4; ++i){
    int cc = tid + 256*i; int row = cc >> 3, d0 = (cc & 7)*8;
    unsigned short t[8]; unpack8(*(const uint4*)(qp + row*64 + d0), t);
    #pragma unroll
    for (int u = 0; u < 8; ++u) pq[row*72 + d0 + u] = f2bf(phi_f(bf2f(t[u])));
  }
  #pragma unroll
  for (int i = 0; i < 16; ++i){
    int f = tid + 256*i; int d = f >> 6, e = f & 63;   // Sp is d-major [d][e]
    SpT[e*72 + d] = f2bf(Sp[f]);                        // SpT rows e, cols d
  }
  if (tid < 64) zp[tid] = zpg[tid];

  float den[2][4] = {};
  f32x4 accO[2][4] = {};

  for (int kh = 0; kh < 2; ++kh){
    __syncthreads();
    #pragma unroll
    for (int i = 0; i < 2; ++i){
      int cc = tid + 256*i; int kr = cc >> 3, d0 = (cc & 7)*8;
      unsigned short t[8]; unpack8(*(const uint4*)(kp + (kh*64+kr)*64 + d0), t);
      #pragma unroll
      for (int u = 0; u < 8; ++u) pk[kr*72 + d0 + u] = f2bf(phi_f(bf2f(t[u])));
      *(uint4*)&vT[kr*72 + d0] = *(const uint4*)&vp[(size_t)kr*gS + s0 + kh*64 + d0];
    }
    __syncthreads();

    f32x4 sc[2][4] = {};
    #pragma unroll
    for (int kk = 0; kk < 64; kk += 32){
      bf16x8 a[2];
      #pragma unroll
      for (int rt = 0; rt < 2; ++rt) a[rt] = *(const bf16x8*)&pq[(32*w+16*rt+lr)*72 + kk + 8*lg];
      #pragma unroll
      for (int ct = 0; ct < 4; ++ct){
        bf16x8 bk = *(const bf16x8*)&pk[(16*ct+lr)*72 + kk + 8*lg];
        #pragma unroll
        for (int rt = 0; rt < 2; ++rt)
          sc[rt][ct] = __builtin_amdgcn_mfma_f32_16x16x32_bf16(a[rt], bk, sc[rt][ct], 0, 0, 0);
      }
    }
    #pragma unroll
    for (int rt = 0; rt < 2; ++rt)
      #pragma unroll
      for (int ct = 0; ct < 4; ++ct)
        #pragma unroll
        for (int r = 0; r < 4; ++r){
          int qrow = 32*w + 16*rt + 4*lg + r;
          int krow = kh*64 + 16*ct + lr;
          float sv = (krow <= qrow) ? sc[rt][ct][r] : 0.f;
          den[rt][r] += sv;
          Ph[qrow*72 + 16*ct + lr] = f2bf(sv);
        }
    #pragma unroll
    for (int kk = 0; kk < 64; kk += 32){
      bf16x8 ap[2];
      #pragma unroll
      for (int rt = 0; rt < 2; ++rt) ap[rt] = *(const bf16x8*)&Ph[(32*w+16*rt+lr)*72 + kk + 8*lg];
      #pragma unroll
      for (int et = 0; et < 4; ++et){
        bf16x8 bv = *(const bf16x8*)&vT[(16*et+lr)*72 + kk + 8*lg];
        #pragma unroll
        for (int rt = 0; rt < 2; ++rt)
          accO[rt][et] = __builtin_amdgcn_mfma_f32_16x16x32_bf16(ap[rt], bv, accO[rt][et], 0, 0, 0);
      }
    }
  }
  #pragma unroll
  for (int kk = 0; kk < 64; kk += 32){
    bf16x8 a[2];
    #pragma unroll
    for (int rt = 0; rt < 2; ++rt) a[rt] = *(const bf16x8*)&pq[(32*w+16*rt+lr)*72 + kk + 8*lg];
    #pragma unroll
    for (int et = 0; et < 4; ++et){
      bf16x8 bs = *(const bf16x8*)&SpT[(16*et+lr)*72 + kk + 8*lg];
      #pragma unroll
      for (int rt = 0; rt < 2; ++rt)
        accO[rt][et] = __builtin_amdgcn_mfma_f32_16x16x32_bf16(a[rt], bs, accO[rt][et], 0, 0, 0);
    }
  }
  #pragma unroll
  for (int rt = 0; rt < 2; ++rt)
    #pragma unroll
    for (int r = 0; r < 4; ++r){
      int qrow = 32*w + 16*rt + 4*lg + r;
      float part = 0.f;
      #pragma unroll
      for (int u = 0; u < 4; ++u){
        int d = 4*lr + u;
        part += bf2f(pq[qrow*72 + d]) * zp[d];
      }
      den[rt][r] += part;
      #pragma unroll
      for (int off = 1; off < 16; off <<= 1)
        den[rt][r] += __shfl_xor(den[rt][r], off);
    }
  #pragma unroll
  for (int rt = 0; rt < 2; ++rt)
    #pragma unroll
    for (int et = 0; et < 4; ++et)
      #pragma unroll
      for (int r = 0; r < 4; ++r){
        int qrow = 32*w + 16*rt + 4*lg + r;
        int e = 16*et + lr;
        float o = accO[rt][et][r] / (den[rt][r] + 1e-6f);
        int s = s0 + qrow;
        size_t idx = ((size_t)(b*gS+s)*gH + h)*64 + e;
        hout[idx] = f2bf(bf2f(olocal[idx]) + 0.5f * o);
      }
}

// ---------------- host launch ----------------
extern "C" void kernel_launch(void* const* d_in, const int* in_sizes, int n_in,
                              void* d_out, int out_size, void* d_ws, size_t ws_size,
                              hipStream_t stream)
{
  const float* hidden = (const float*)d_in[0];
  const float* cosb   = (const float*)d_in[1];
  const float* sinb   = (const float*)d_in[2];
  const float* Wq     = (const float*)d_in[3];
  const float* Wk     = (const float*)d_in[4];
  const float* Wv     = (const float*)d_in[5];
  const float* Wo     = (const float*)d_in[6];
  float* out = (float*)d_out;

  char* ws = (char*)d_ws;
  size_t off = 0;
  auto alloc = [&](size_t bytes)->void*{
    void* p = ws + off; off += (bytes + 255) & ~(size_t)255; return p;
  };
  unsigned short* hbf    = (unsigned short*)alloc((size_t)gBS*gHID*2);   // hidden bf16; reused as hybrid bf16
  unsigned short* wqkv   = (unsigned short*)alloc((size_t)3072*gHID*2);  // [Wq;Wk;Wv]
  unsigned short* wob    = (unsigned short*)alloc((size_t)gHID*gHID*2);
  unsigned short* vproj  = (unsigned short*)alloc((size_t)gBS*512*2);    // (B,S,KVH*64)
  unsigned short* q_r    = (unsigned short*)alloc((size_t)gBS*gHID*2);   // (B,H,S,64)
  unsigned short* k_r    = (unsigned short*)alloc((size_t)gBS*512*2);    // (B,KVH,S,64)
  unsigned short* ktr    = (unsigned short*)alloc((size_t)gBS*512*2);    // (B,KVH,64,S)
  unsigned short* vt     = (unsigned short*)alloc((size_t)gBS*512*2);    // (B,KVH,64,S)
  unsigned short* olocal = (unsigned short*)alloc((size_t)gBS*gHID*2);
  float* kvbuf           = (float*)alloc((size_t)gB*gKVH*gNC*4096*4);    // d-major; scanned in place
  float* ksbuf           = (float*)alloc((size_t)gB*gKVH*gNC*64*4);

  // fused convert: hidden + Wq + Wk + Wv + Wo in one launch
  cvt_all<<<dim3(2048), dim3(256), 0, stream>>>(hidden, Wq, Wk, Wv, Wo, hbf, wqkv, wob);

  // fused QKV projection + RoPE + layout (q_r, k_r, vproj)
  gemm_qkv<<<dim3(64*12), dim3(512), 0, stream>>>(hbf, wqkv, cosb, sinb, q_r, k_r, vproj);

  transpose64<<<dim3(gB*gKVH*64), dim3(256), 0, stream>>>(k_r,   ktr, 64,  0, 0);
  transpose64<<<dim3(gB*gKVH*64), dim3(256), 0, stream>>>(vproj, vt,  512, 0, 1);

  local_attn<<<dim3(gB*gH*32), dim3(512), 0, stream>>>(q_r, k_r, vt, olocal);
  lin_pass1<<<dim3(gB*gKVH*gNC), dim3(256), 0, stream>>>(ktr, vt, kvbuf, ksbuf);
  lin_pass2<<<dim3((gB*gKVH*(4096+64) + 255)/256), dim3(256), 0, stream>>>(kvbuf, ksbuf);
  lin_pass3<<<dim3(gB*gH*gNC), dim3(256), 0, stream>>>(q_r, k_r, vt, kvbuf, ksbuf, olocal, hbf);

  gemm256<0><<<dim3(32*8), dim3(512), 0, stream>>>(hbf, wob, (void*)out, 8192, 2048, 2048);
}

// Round 15
// 328.661 us; speedup vs baseline: 1.1462x; 1.0030x over previous
//
#include <hip/hip_runtime.h>

// ---------------- problem constants ----------------
#define gB 2
#define gS 4096
#define gH 32
#define gKVH 8
#define gHID 2048
#define gNC 32            // S / CHK
#define gBS (gB*gS)       // 8192
// D = 64, WIN = 256, CHK = 128, NREP = 4 are hard-coded below.

using bf16x8 = __attribute__((ext_vector_type(8))) short;
using f32x4  = __attribute__((ext_vector_type(4))) float;

__device__ __forceinline__ float bf2f(unsigned short u){
  return __uint_as_float(((unsigned)u) << 16);
}
__device__ __forceinline__ unsigned short f2bf(float f){
  unsigned u = __float_as_uint(f);
  u = (u + 0x7fffu + ((u >> 16) & 1u)) >> 16;   // RNE
  return (unsigned short)u;
}
__device__ __forceinline__ float phi_f(float x){ return x > 0.f ? x + 1.f : __expf(x); } // elu(x)+1

__device__ __forceinline__ void unpack8(uint4 v, unsigned short* o){
  o[0]=(unsigned short)(v.x&0xffffu); o[1]=(unsigned short)(v.x>>16);
  o[2]=(unsigned short)(v.y&0xffffu); o[3]=(unsigned short)(v.y>>16);
  o[4]=(unsigned short)(v.z&0xffffu); o[5]=(unsigned short)(v.z>>16);
  o[6]=(unsigned short)(v.w&0xffffu); o[7]=(unsigned short)(v.w>>16);
}
__device__ __forceinline__ uint4 pack8(const unsigned short* s){
  uint4 v;
  v.x = (unsigned)s[0] | ((unsigned)s[1]<<16);
  v.y = (unsigned)s[2] | ((unsigned)s[3]<<16);
  v.z = (unsigned)s[4] | ((unsigned)s[5]<<16);
  v.w = (unsigned)s[6] | ((unsigned)s[7]<<16);
  return v;
}

// async global->LDS, 16B per lane; LDS dest = wave-uniform base + lane*16
typedef const __attribute__((address_space(1))) void* gas_ptr;
typedef __attribute__((address_space(3))) void* las_ptr;
__device__ __forceinline__ void gload16(const void* g, void* l){
  __builtin_amdgcn_global_load_lds((gas_ptr)g, (las_ptr)l, 16, 0, 0);
}

// ---------------- fused f32 -> bf16 convert (hidden + Wq + Wk + Wv + Wo, 1 launch) ----------------
__global__ void cvt_all(const float* __restrict__ hidden, const float* __restrict__ Wq,
                        const float* __restrict__ Wk, const float* __restrict__ Wv,
                        const float* __restrict__ Wo, unsigned short* __restrict__ hbf,
                        unsigned short* __restrict__ wqkv, unsigned short* __restrict__ wob)
{
  const long HG = (long)gBS*gHID/4;        // 4,194,304 groups of 4 floats
  const long QG = 1048576, KG = 262144, VG = 262144, OG = 1048576;
  const long total = HG + QG + KG + VG + OG;
  long stride = (long)gridDim.x * blockDim.x;
  for (long i = (long)blockIdx.x*blockDim.x + threadIdx.x; i < total; i += stride){
    const float* src; unsigned short* dst; long off;
    if (i < HG)                { src = hidden; dst = hbf;                          off = i; }
    else if (i < HG+QG)        { src = Wq;     dst = wqkv;                         off = i - HG; }
    else if (i < HG+QG+KG)     { src = Wk;     dst = wqkv + (size_t)2048*gHID;     off = i - HG - QG; }
    else if (i < HG+QG+KG+VG)  { src = Wv;     dst = wqkv + (size_t)2560*gHID;     off = i - HG - QG - KG; }
    else                       { src = Wo;     dst = wob;                          off = i - HG - QG - KG - VG; }
    float4 v = *(const float4*)(src + off*4);
    ushort4 o;
    o.x = f2bf(v.x); o.y = f2bf(v.y); o.z = f2bf(v.z); o.w = f2bf(v.w);
    *(ushort4*)(dst + off*4) = o;
  }
}

// ---------------- QKV GEMM 128x256, BK=64, 2-buffer, 1 barrier/K-tile ----------------
// round-11 loop + HOISTED stage addressing (per-tile stage = 6 x (base + t*128)).
__global__ __launch_bounds__(512, 2) void gemm_qkv(const unsigned short* __restrict__ A,
                                                   const unsigned short* __restrict__ Bm,
                                                   const float* __restrict__ cosb,
                                                   const float* __restrict__ sinb,
                                                   unsigned short* __restrict__ q_r,
                                                   unsigned short* __restrict__ k_r,
                                                   unsigned short* __restrict__ vproj)
{
  const int Kdim = 2048;
  __shared__ unsigned short Sh[2*24576];   // buf stride 49152 B: A (16 KB) + B (32 KB)
  int tid = threadIdx.x, lane = tid & 63, w = tid >> 6, lr = lane & 15, lg = lane >> 4;
  int wm = w >> 2, wn = w & 3;
  const int ntn = 12;                      // 3072/256
  int nwg = gridDim.x;
  int bid = (int)blockIdx.x;
  int swz = (bid & 7) * (nwg >> 3) + (bid >> 3);   // XCD-chunked (nwg % 8 == 0)
  long m0 = (long)(swz / ntn) * 128;
  long n0 = (long)(swz % ntn) * 256;
  const int NT = Kdim >> 6;                // 32

  f32x4 acc[4][4] = {};

  // t-invariant stage bases (k advances 128 B per tile)
  const char* gsrc[6]; unsigned ldst[6];
  #pragma unroll
  for (int i = 0; i < 2; ++i){             // A: 1024 chunks (128 rows x 8)
    int c = w*64 + lane + i*512;
    int row = c >> 3, g = c & 7;
    int colb = (g ^ (row & 7)) << 4;
    gsrc[i] = (const char*)A + ((m0 + row) * (long)Kdim)*2 + colb;
    ldst[i] = (unsigned)((w*64 + i*512)*16);
  }
  #pragma unroll
  for (int i = 0; i < 4; ++i){             // B: 2048 chunks (256 rows x 8)
    int c = w*64 + lane + i*512;
    int row = c >> 3, g = c & 7;
    int colb = (g ^ (row & 7)) << 4;
    gsrc[2+i] = (const char*)Bm + ((n0 + row) * (long)Kdim)*2 + colb;
    ldst[2+i] = (unsigned)(16384 + (w*64 + i*512)*16);
  }
  auto stage = [&](int t){
    int sb = (t & 1) * 49152;              // bytes
    long kb = (long)t << 7;                // t*128 bytes
    #pragma unroll
    for (int i = 0; i < 6; ++i)
      gload16(gsrc[i] + kb, (char*)Sh + sb + ldst[i]);
  };

  stage(0);
  for (int t = 0; t < NT; ++t){
    asm volatile("s_waitcnt vmcnt(0)" ::: "memory");
    __builtin_amdgcn_s_barrier();
    if (t + 1 < NT) stage(t + 1);
    int sb = (t & 1) * 24576;              // shorts
    #pragma unroll
    for (int kk = 0; kk < 2; ++kk){
      bf16x8 af[4], bfr[4];
      #pragma unroll
      for (int m = 0; m < 4; ++m){
        int row = wm*64 + m*16 + lr;
        af[m] = *(const bf16x8*)&Sh[sb + row*64 + (((kk*4 + lg) ^ (row & 7)) << 3)];
      }
      #pragma unroll
      for (int n = 0; n < 4; ++n){
        int row = wn*64 + n*16 + lr;
        bfr[n] = *(const bf16x8*)&Sh[sb + 8192 + row*64 + (((kk*4 + lg) ^ (row & 7)) << 3)];
      }
      __builtin_amdgcn_s_setprio(1);
      #pragma unroll
      for (int m = 0; m < 4; ++m)
        #pragma unroll
        for (int n = 0; n < 4; ++n)
          acc[m][n] = __builtin_amdgcn_mfma_f32_16x16x32_bf16(af[m], bfr[n], acc[m][n], 0, 0, 0);
      __builtin_amdgcn_s_setprio(0);
    }
  }

  // ---- fused epilogue. C/D layout: col = lane&15, row = 4*(lane>>4) + reg ----
  long colbase = n0 + wn*64;                 // 64-aligned; block section-uniform
  if (colbase < 2048){
    int head = (int)(colbase >> 6);
    #pragma unroll
    for (int m = 0; m < 4; ++m)
      #pragma unroll
      for (int r = 0; r < 4; ++r){
        long srow = m0 + wm*64 + m*16 + 4*lg + r;   // = b*gS + s
        int b = (int)(srow >> 12), s = (int)(srow & 4095);
        const float* cp = cosb + srow*64;
        const float* sp = sinb + srow*64;
        unsigned short* op = q_r + ((size_t)(b*gH + head)*gS + s)*64;
        #pragma unroll
        for (int n = 0; n < 2; ++n){
          int d = n*16 + lr;
          float x1 = acc[m][n][r], x2 = acc[m][n+2][r];
          op[d]      = f2bf(x1*cp[d]    - x2*sp[d]);
          op[d+32]   = f2bf(x2*cp[d+32] + x1*sp[d+32]);
        }
      }
  } else if (colbase < 2560){
    int head = (int)(colbase >> 6) - 32;
    #pragma unroll
    for (int m = 0; m < 4; ++m)
      #pragma unroll
      for (int r = 0; r < 4; ++r){
        long srow = m0 + wm*64 + m*16 + 4*lg + r;
        int b = (int)(srow >> 12), s = (int)(srow & 4095);
        const float* cp = cosb + srow*64;
        const float* sp = sinb + srow*64;
        unsigned short* op = k_r + ((size_t)(b*gKVH + head)*gS + s)*64;
        #pragma unroll
        for (int n = 0; n < 2; ++n){
          int d = n*16 + lr;
          float x1 = acc[m][n][r], x2 = acc[m][n+2][r];
          op[d]      = f2bf(x1*cp[d]    - x2*sp[d]);
          op[d+32]   = f2bf(x2*cp[d+32] + x1*sp[d+32]);
        }
      }
  } else {
    #pragma unroll
    for (int m = 0; m < 4; ++m)
      #pragma unroll
      for (int r = 0; r < 4; ++r){
        long srow = m0 + wm*64 + m*16 + 4*lg + r;
        unsigned short* op = vproj + (size_t)srow*512 + (colbase - 2560);
        #pragma unroll
        for (int n = 0; n < 4; ++n)
          op[n*16 + lr] = f2bf(acc[m][n][r]);
      }
  }
}

// ---------------- GEMM 256x256, BK=64, 2-buffer, 1 barrier/K-tile (Wo) ----------------
// round-11 loop + hoisted stage addressing.
template<int OUT_BF16>
__global__ __launch_bounds__(512, 2) void gemm256(const unsigned short* __restrict__ A,
                                                  const unsigned short* __restrict__ Bm,
                                                  void* __restrict__ Cout,
                                                  int Mdim, int Ndim, int Kdim)
{
  __shared__ unsigned short Sh[2*32768];   // buf stride 65536 B: A (32 KB) + B (32 KB)
  int tid = threadIdx.x, lane = tid & 63, w = tid >> 6, lr = lane & 15, lg = lane >> 4;
  int wm = w >> 2, wn = w & 3;
  int ntn = Ndim >> 8;
  int nwg = gridDim.x;
  int bid = (int)blockIdx.x;
  int swz = (bid & 7) * (nwg >> 3) + (bid >> 3);   // XCD-chunked (nwg % 8 == 0)
  long m0 = (long)(swz / ntn) * 256;
  long n0 = (long)(swz % ntn) * 256;
  int NT = Kdim >> 6;

  f32x4 acc[8][4] = {};

  const char* gsrc[8]; unsigned ldst[8];
  #pragma unroll
  for (int i = 0; i < 4; ++i){             // A and B: 2048 chunks each (256 rows x 8)
    int c = w*64 + lane + i*512;
    int row = c >> 3, g = c & 7;
    int colb = (g ^ (row & 7)) << 4;
    gsrc[i]   = (const char*)A  + ((m0 + row) * (long)Kdim)*2 + colb;
    ldst[i]   = (unsigned)((w*64 + i*512)*16);
    gsrc[4+i] = (const char*)Bm + ((n0 + row) * (long)Kdim)*2 + colb;
    ldst[4+i] = (unsigned)(32768 + (w*64 + i*512)*16);
  }
  auto stage = [&](int t){
    int sb = (t & 1) * 65536;              // bytes
    long kb = (long)t << 7;
    #pragma unroll
    for (int i = 0; i < 8; ++i)
      gload16(gsrc[i] + kb, (char*)Sh + sb + ldst[i]);
  };

  stage(0);
  for (int t = 0; t < NT; ++t){
    asm volatile("s_waitcnt vmcnt(0)" ::: "memory");
    __builtin_amdgcn_s_barrier();
    if (t + 1 < NT) stage(t + 1);
    int sb = (t & 1) * 32768;              // shorts
    #pragma unroll
    for (int kk = 0; kk < 2; ++kk){
      bf16x8 af[8], bfr[4];
      #pragma unroll
      for (int m = 0; m < 8; ++m){
        int row = wm*128 + m*16 + lr;
        af[m] = *(const bf16x8*)&Sh[sb + row*64 + (((kk*4 + lg) ^ (row & 7)) << 3)];
      }
      #pragma unroll
      for (int n = 0; n < 4; ++n){
        int row = wn*64 + n*16 + lr;
        bfr[n] = *(const bf16x8*)&Sh[sb + 16384 + row*64 + (((kk*4 + lg) ^ (row & 7)) << 3)];
      }
      __builtin_amdgcn_s_setprio(1);
      #pragma unroll
      for (int m = 0; m < 8; ++m)
        #pragma unroll
        for (int n = 0; n < 4; ++n)
          acc[m][n] = __builtin_amdgcn_mfma_f32_16x16x32_bf16(af[m], bfr[n], acc[m][n], 0, 0, 0);
      __builtin_amdgcn_s_setprio(0);
    }
  }

  // epilogue: C/D layout col = lane&15, row = 4*(lane>>4) + reg
  #pragma unroll
  for (int m = 0; m < 8; ++m)
    #pragma unroll
    for (int n = 0; n < 4; ++n)
      #pragma unroll
      for (int r = 0; r < 4; ++r){
        long row = m0 + wm*128 + m*16 + 4*lg + r;
        long col = n0 + wn*64 + n*16 + lr;
        float v = acc[m][n][r];
        if (OUT_BF16) ((unsigned short*)Cout)[row*Ndim + col] = f2bf(v);
        else          ((float*)Cout)[row*Ndim + col] = v;
      }
}

// ---------------- fused transposes: k_r -> ktr (mode0) and vproj -> vt (mode1), one launch ----------------
__global__ __launch_bounds__(256) void transpose2(const unsigned short* __restrict__ k_r,
                                                  unsigned short* __restrict__ ktr,
                                                  const unsigned short* __restrict__ vproj,
                                                  unsigned short* __restrict__ vt)
{
  __shared__ unsigned short T[64*72];
  int bid = blockIdx.x;
  int mode = bid >> 10; bid &= 1023;
  int st = bid & 63; int kvh = (bid >> 6) & 7; int b = bid >> 9;
  int s0 = st*64;
  int tid = threadIdx.x;
  const unsigned short* ip;
  unsigned short* out;
  size_t tokstr;
  if (mode == 0){ ip = k_r + ((size_t)(b*gKVH+kvh)*gS + s0)*64;      out = ktr; tokstr = 64; }
  else          { ip = vproj + (size_t)(b*gS+s0)*512 + kvh*64;       out = vt;  tokstr = 512; }
  #pragma unroll
  for (int i = 0; i < 2; ++i){
    int cc = tid + 256*i; int sl = cc >> 3, ch = cc & 7;
    *(uint4*)&T[sl*72 + ch*8] = *(const uint4*)&ip[(size_t)sl*tokstr + ch*8];
  }
  __syncthreads();
  unsigned short* op = out + ((size_t)(b*gKVH+kvh)*64)*gS;
  #pragma unroll
  for (int i = 0; i < 2; ++i){
    int cc = tid + 256*i; int d = cc >> 3, ch = cc & 7;
    unsigned short t[8];
    #pragma unroll
    for (int u = 0; u < 8; ++u) t[u] = T[(ch*8+u)*72 + d];
    *(uint4*)&op[(size_t)d*gS + s0 + ch*8] = pack8(t);
  }
}

// ---------------- local sliding-window attention (v3: no-max softmax) ----------------
__global__ __launch_bounds__(512) void local_attn(const unsigned short* __restrict__ q_r,
                                                  const unsigned short* __restrict__ k_r,
                                                  const unsigned short* __restrict__ vt,
                                                  unsigned short* __restrict__ olocal)
{
  __shared__ unsigned short Qs[128*72];
  __shared__ unsigned short Ks[2][64*72];
  __shared__ unsigned short VTs[2][64*72];
  __shared__ unsigned short Ps[8*16*72];
  int bid = blockIdx.x;
  int qt = bid & 31; int h = (bid >> 5) & 31; int b = bid >> 10;
  int kvh = h >> 2;
  int q0 = qt*128;
  int tid = threadIdx.x, lane = tid & 63, w = tid >> 6, lr = lane & 15, lg = lane >> 4;
  const unsigned short* qp = q_r + ((size_t)(b*gH  +h  )*gS + q0)*64;
  const unsigned short* kp = k_r + ((size_t)(b*gKVH+kvh)*gS)*64;
  const unsigned short* vp = vt  + ((size_t)(b*gKVH+kvh)*64)*gS;   // rows d, stride S

  #pragma unroll
  for (int i = 0; i < 2; ++i){
    int cc = tid + 512*i; int row = cc >> 3, ch = cc & 7;
    *(uint4*)&Qs[row*72 + ch*8] = *(const uint4*)&qp[row*64 + ch*8];
  }

  int kt0 = (q0 >= 256) ? 0 : ((256 - q0) >> 6);
  int krow = tid >> 3, kch = tid & 7;       // 64 rows x 8 chunks = 512 threads
  uint4 kreg, vreg;
  {
    int kb = q0 - 256 + kt0*64;
    kreg = *(const uint4*)&kp[(size_t)(kb+krow)*64 + kch*8];
    vreg = *(const uint4*)&vp[(size_t)krow*gS + kb + kch*8];
    *(uint4*)&Ks[0][krow*72 + kch*8]  = kreg;
    *(uint4*)&VTs[0][krow*72 + kch*8] = vreg;
  }

  float psum[4] = {0.f, 0.f, 0.f, 0.f};
  f32x4 accO[4] = {};
  int wq = w*16;

  for (int kt = kt0; kt < 6; ++kt){
    int cur = (kt - kt0) & 1;
    __syncthreads();
    bool more = (kt + 1 < 6);
    if (more){
      int kb2 = q0 - 256 + (kt+1)*64;
      kreg = *(const uint4*)&kp[(size_t)(kb2+krow)*64 + kch*8];
      vreg = *(const uint4*)&vp[(size_t)krow*gS + kb2 + kch*8];
    }

    f32x4 sc[4] = {};
    #pragma unroll
    for (int kk = 0; kk < 64; kk += 32){
      bf16x8 aq = *(const bf16x8*)&Qs[(wq+lr)*72 + kk + 8*lg];
      #pragma unroll
      for (int f = 0; f < 4; ++f){
        bf16x8 bk = *(const bf16x8*)&Ks[cur][(f*16+lr)*72 + kk + 8*lg];
        sc[f] = __builtin_amdgcn_mfma_f32_16x16x32_bf16(aq, bk, sc[f], 0, 0, 0);
      }
    }
    // no-max softmax accumulation: p = keep ? exp(s/8) : 0
    #pragma unroll
    for (int f = 0; f < 4; ++f)
      #pragma unroll
      for (int r = 0; r < 4; ++r){
        int i = wq + 4*lg + r;               // local query row (0..127)
        int j = kt*64 + f*16 + lr;           // window column (0..383)
        bool keep = (j > i) && (j <= i + 256);
        float e = __expf(sc[f][r] * 0.125f);
        float p = keep ? e : 0.f;
        psum[r] += p;
        Ps[w*1152 + (4*lg + r)*72 + f*16 + lr] = f2bf(p);
      }
    // Ps write->read is same-wave LDS (in-order DS pipe) — no barrier needed.
    #pragma unroll
    for (int kk = 0; kk < 64; kk += 32){
      bf16x8 ap = *(const bf16x8*)&Ps[w*1152 + lr*72 + kk + 8*lg];
      #pragma unroll
      for (int dt = 0; dt < 4; ++dt){
        bf16x8 bv = *(const bf16x8*)&VTs[cur][(dt*16+lr)*72 + kk + 8*lg];
        accO[dt] = __builtin_amdgcn_mfma_f32_16x16x32_bf16(ap, bv, accO[dt], 0, 0, 0);
      }
    }
    if (more){
      *(uint4*)&Ks[cur^1][krow*72 + kch*8]  = kreg;
      *(uint4*)&VTs[cur^1][krow*72 + kch*8] = vreg;
    }
  }
  // single 16-lane-group row-sum reduce
  #pragma unroll
  for (int off = 1; off < 16; off <<= 1)
    #pragma unroll
    for (int r = 0; r < 4; ++r) psum[r] += __shfl_xor(psum[r], off);
  #pragma unroll
  for (int dt = 0; dt < 4; ++dt)
    #pragma unroll
    for (int r = 0; r < 4; ++r){
      int s = q0 + wq + 4*lg + r;
      int d = dt*16 + lr;
      float o = accO[dt][r] / psum[r];
      olocal[((size_t)(b*gS+s)*gH + h)*64 + d] = f2bf(0.5f * o);
    }
}

// ---------------- linear attention pass 1 ----------------
__global__ __launch_bounds__(256) void lin_pass1(const unsigned short* __restrict__ ktr,
                                                 const unsigned short* __restrict__ vt,
                                                 float* __restrict__ kvbuf, float* __restrict__ ksbuf)
{
  __shared__ unsigned short pkT[64*136];
  __shared__ unsigned short vT[64*136];
  int bid = blockIdx.x;
  int c = bid & 31; int kvh = (bid >> 5) & 7; int b = bid >> 8;
  int tid = threadIdx.x, lane = tid & 63, w = tid >> 6, lr = lane & 15, lg = lane >> 4;
  int s0 = c*128;
  const unsigned short* kp = ktr + ((size_t)(b*gKVH+kvh)*64)*gS;
  const unsigned short* vp = vt  + ((size_t)(b*gKVH+kvh)*64)*gS;
  #pragma unroll
  for (int i = 0; i < 4; ++i){
    int cc = tid + 256*i; int d = cc >> 4, ch = cc & 15;
    unsigned short t[8]; unpack8(*(const uint4*)&kp[(size_t)d*gS + s0 + ch*8], t);
    #pragma unroll
    for (int u = 0; u < 8; ++u) t[u] = f2bf(phi_f(bf2f(t[u])));
    *(uint4*)&pkT[d*136 + ch*8] = pack8(t);
    *(uint4*)&vT[d*136 + ch*8]  = *(const uint4*)&vp[(size_t)d*gS + s0 + ch*8];
  }
  __syncthreads();
  f32x4 acc[4] = {};
  #pragma unroll
  for (int kk = 0; kk < 128; kk += 32){
    bf16x8 a = *(const bf16x8*)&pkT[(16*w+lr)*136 + kk + 8*lg];
    #pragma unroll
    for (int et = 0; et < 4; ++et){
      bf16x8 bv = *(const bf16x8*)&vT[(16*et+lr)*136 + kk + 8*lg];
      acc[et] = __builtin_amdgcn_mfma_f32_16x16x32_bf16(a, bv, acc[et], 0, 0, 0);
    }
  }
  size_t base = (size_t)((b*gKVH+kvh)*gNC + c);
  float* kvp = kvbuf + base*4096;
  #pragma unroll
  for (int et = 0; et < 4; ++et)
    #pragma unroll
    for (int r = 0; r < 4; ++r)
      kvp[(16*w + 4*lg + r)*64 + 16*et + lr] = acc[et][r];   // d-major [d][e]
  if (tid < 64){
    float sum = 0.f;
    for (int k = 0; k < 128; ++k) sum += bf2f(pkT[tid*136 + k]);
    ksbuf[base*64 + tid] = sum;
  }
}

// ---------------- linear attention pass 2: in-place exclusive scan (d-major kept) ----------------
__global__ void lin_pass2(float* __restrict__ kvbuf, float* __restrict__ ksbuf){
  int t = blockIdx.x*256 + threadIdx.x;
  const int per = 4096 + 64;
  if (t >= gB*gKVH*per) return;
  int bh = t / per; int e = t % per;
  if (e < 4096){
    float* p = kvbuf + (size_t)bh*gNC*4096 + e;   // coalesced read AND write
    float acc = 0.f;
    for (int cix = 0; cix < gNC; ++cix){ float v = p[(size_t)cix*4096]; p[(size_t)cix*4096] = acc; acc += v; }
  } else {
    float* p = ksbuf + (size_t)bh*gNC*64 + (e - 4096);
    float acc = 0.f;
    for (int cix = 0; cix < gNC; ++cix){ float v = p[cix*64]; p[cix*64] = acc; acc += v; }
  }
}

// ---------------- linear attention pass 3 (+ fused combine: hout = olocal + 0.5*lin) ----------------
// Sprev is d-major [d][e] (kvbuf after in-place scan).
__global__ __launch_bounds__(256) void lin_pass3(const unsigned short* __restrict__ q_r,
                                                 const unsigned short* __restrict__ k_r,
                                                 const unsigned short* __restrict__ vt,
                                                 const float* __restrict__ Sprev,
                                                 const float* __restrict__ zprev,
                                                 const unsigned short* __restrict__ olocal,
                                                 unsigned short* __restrict__ hout)
{
  __shared__ unsigned short pq[128*72];
  __shared__ unsigned short pk[64*72];
  __shared__ unsigned short Ph[128*72];
  __shared__ unsigned short vT[64*72];
  __shared__ unsigned short SpT[64*72];
  __shared__ float zp[64];

  int bid = blockIdx.x;
  int c = bid & 31; int h = (bid >> 5) & 31; int b = bid >> 10;
  int kvh = h >> 2;
  int tid = threadIdx.x, lane = tid & 63, w = tid >> 6, lr = lane & 15, lg = lane >> 4;
  int s0 = c*128;
  const unsigned short* qp = q_r + ((size_t)(b*gH  +h  )*gS + s0)*64;
  const unsigned short* kp = k_r + ((size_t)(b*gKVH+kvh)*gS + s0)*64;
  const unsigned short* vp = vt  + ((size_t)(b*gKVH+kvh)*64)*gS;
  const float* Sp  = Sprev + ((size_t)((b*gKVH+kvh)*gNC + c))*4096;
  const float* zpg = zprev + ((size_t)((b*gKVH+kvh)*gNC + c))*64;

  #pragma unroll
  for (int i = 0; i < 4; ++i){
    int cc = tid + 256*i; int row = cc >> 3, d0 = (cc & 7)*8;
    unsigned short t[8]; unpack8(*(const uint4*)(qp + row*64 + d0), t);
    #pragma unroll
    for (int u = 0; u < 8; ++u) t[u] = f2bf(phi_f(bf2f(t[u])));
    *(uint4*)&pq[row*72 + d0] = pack8(t);
  }
  #pragma unroll
  for (int i = 0; i < 16; ++i){
    int f = tid + 256*i; int d = f >> 6, e = f & 63;   // Sp is d-major [d][e]
    SpT[e*72 + d] = f2bf(Sp[f]);                        // SpT rows e, cols d
  }
  if (tid < 64) zp[tid] = zpg[tid];

  float den[2][4] = {};
  f32x4 accO[2][4] = {};

  for (int kh = 0; kh < 2; ++kh){
    __syncthreads();
    #pragma unroll
    for (int i = 0; i < 2; ++i){
      int cc = tid + 256*i; int kr = cc >> 3, d0 = (cc & 7)*8;
      unsigned short t[8]; unpack8(*(const uint4*)(kp + (kh*64+kr)*64 + d0), t);
      #pragma unroll
      for (int u = 0; u < 8; ++u) t[u] = f2bf(phi_f(bf2f(t[u])));
      *(uint4*)&pk[kr*72 + d0] = pack8(t);
      *(uint4*)&vT[kr*72 + d0] = *(const uint4*)&vp[(size_t)kr*gS + s0 + kh*64 + d0];
    }
    __syncthreads();

    f32x4 sc[2][4] = {};
    #pragma unroll
    for (int kk = 0; kk < 64; kk += 32){
      bf16x8 a[2];
      #pragma unroll
      for (int rt = 0; rt < 2; ++rt) a[rt] = *(const bf16x8*)&pq[(32*w+16*rt+lr)*72 + kk + 8*lg];
      #pragma unroll
      for (int ct = 0; ct < 4; ++ct){
        bf16x8 bk = *(const bf16x8*)&pk[(16*ct+lr)*72 + kk + 8*lg];
        #pragma unroll
        for (int rt = 0; rt < 2; ++rt)
          sc[rt][ct] = __builtin_amdgcn_mfma_f32_16x16x32_bf16(a[rt], bk, sc[rt][ct], 0, 0, 0);
      }
    }
    #pragma unroll
    for (int rt = 0; rt < 2; ++rt)
      #pragma unroll
      for (int ct = 0; ct < 4; ++ct)
        #pragma unroll
        for (int r = 0; r < 4; ++r){
          int qrow = 32*w + 16*rt + 4*lg + r;
          int krow = kh*64 + 16*ct + lr;
          float sv = (krow <= qrow) ? sc[rt][ct][r] : 0.f;
          den[rt][r] += sv;
          Ph[qrow*72 + 16*ct + lr] = f2bf(sv);
        }
    #pragma unroll
    for (int kk = 0; kk < 64; kk += 32){
      bf16x8 ap[2];
      #pragma unroll
      for (int rt = 0; rt < 2; ++rt) ap[rt] = *(const bf16x8*)&Ph[(32*w+16*rt+lr)*72 + kk + 8*lg];
      #pragma unroll
      for (int et = 0; et < 4; ++et){
        bf16x8 bv = *(const bf16x8*)&vT[(16*et+lr)*72 + kk + 8*lg];
        #pragma unroll
        for (int rt = 0; rt < 2; ++rt)
          accO[rt][et] = __builtin_amdgcn_mfma_f32_16x16x32_bf16(ap[rt], bv, accO[rt][et], 0, 0, 0);
      }
    }
  }
  #pragma unroll
  for (int kk = 0; kk < 64; kk += 32){
    bf16x8 a[2];
    #pragma unroll
    for (int rt = 0; rt < 2; ++rt) a[rt] = *(const bf16x8*)&pq[(32*w+16*rt+lr)*72 + kk + 8*lg];
    #pragma unroll
    for (int et = 0; et < 4; ++et){
      bf16x8 bs = *(const bf16x8*)&SpT[(16*et+lr)*72 + kk + 8*lg];
      #pragma unroll
      for (int rt = 0; rt < 2; ++rt)
        accO[rt][et] = __builtin_amdgcn_mfma_f32_16x16x32_bf16(a[rt], bs, accO[rt][et], 0, 0, 0);
    }
  }
  #pragma unroll
  for (int rt = 0; rt < 2; ++rt)
    #pragma unroll
    for (int r = 0; r < 4; ++r){
      int qrow = 32*w + 16*rt + 4*lg + r;
      float part = 0.f;
      #pragma unroll
      for (int u = 0; u < 4; ++u){
        int d = 4*lr + u;
        part += bf2f(pq[qrow*72 + d]) * zp[d];
      }
      den[rt][r] += part;
      #pragma unroll
      for (int off = 1; off < 16; off <<= 1)
        den[rt][r] += __shfl_xor(den[rt][r], off);
    }
  #pragma unroll
  for (int rt = 0; rt < 2; ++rt)
    #pragma unroll
    for (int et = 0; et < 4; ++et)
      #pragma unroll
      for (int r = 0; r < 4; ++r){
        int qrow = 32*w + 16*rt + 4*lg + r;
        int e = 16*et + lr;
        float o = accO[rt][et][r] / (den[rt][r] + 1e-6f);
        int s = s0 + qrow;
        size_t idx = ((size_t)(b*gS+s)*gH + h)*64 + e;
        hout[idx] = f2bf(bf2f(olocal[idx]) + 0.5f * o);
      }
}

// ---------------- host launch ----------------
extern "C" void kernel_launch(void* const* d_in, const int* in_sizes, int n_in,
                              void* d_out, int out_size, void* d_ws, size_t ws_size,
                              hipStream_t stream)
{
  const float* hidden = (const float*)d_in[0];
  const float* cosb   = (const float*)d_in[1];
  const float* sinb   = (const float*)d_in[2];
  const float* Wq     = (const float*)d_in[3];
  const float* Wk     = (const float*)d_in[4];
  const float* Wv     = (const float*)d_in[5];
  const float* Wo     = (const float*)d_in[6];
  float* out = (float*)d_out;

  char* ws = (char*)d_ws;
  size_t off = 0;
  auto alloc = [&](size_t bytes)->void*{
    void* p = ws + off; off += (bytes + 255) & ~(size_t)255; return p;
  };
  unsigned short* hbf    = (unsigned short*)alloc((size_t)gBS*gHID*2);   // hidden bf16; reused as hybrid bf16
  unsigned short* wqkv   = (unsigned short*)alloc((size_t)3072*gHID*2);  // [Wq;Wk;Wv]
  unsigned short* wob    = (unsigned short*)alloc((size_t)gHID*gHID*2);
  unsigned short* vproj  = (unsigned short*)alloc((size_t)gBS*512*2);    // (B,S,KVH*64)
  unsigned short* q_r    = (unsigned short*)alloc((size_t)gBS*gHID*2);   // (B,H,S,64)
  unsigned short* k_r    = (unsigned short*)alloc((size_t)gBS*512*2);    // (B,KVH,S,64)
  unsigned short* ktr    = (unsigned short*)alloc((size_t)gBS*512*2);    // (B,KVH,64,S)
  unsigned short* vt     = (unsigned short*)alloc((size_t)gBS*512*2);    // (B,KVH,64,S)
  unsigned short* olocal = (unsigned short*)alloc((size_t)gBS*gHID*2);
  float* kvbuf           = (float*)alloc((size_t)gB*gKVH*gNC*4096*4);    // d-major; scanned in place
  float* ksbuf           = (float*)alloc((size_t)gB*gKVH*gNC*64*4);

  // fused convert: hidden + Wq + Wk + Wv + Wo in one launch
  cvt_all<<<dim3(2048), dim3(256), 0, stream>>>(hidden, Wq, Wk, Wv, Wo, hbf, wqkv, wob);

  // fused QKV projection + RoPE + layout (q_r, k_r, vproj)
  gemm_qkv<<<dim3(64*12), dim3(512), 0, stream>>>(hbf, wqkv, cosb, sinb, q_r, k_r, vproj);

  transpose2<<<dim3(2048), dim3(256), 0, stream>>>(k_r, ktr, vproj, vt);

  local_attn<<<dim3(gB*gH*32), dim3(512), 0, stream>>>(q_r, k_r, vt, olocal);
  lin_pass1<<<dim3(gB*gKVH*gNC), dim3(256), 0, stream>>>(ktr, vt, kvbuf, ksbuf);
  lin_pass2<<<dim3((gB*gKVH*(4096+64) + 255)/256), dim3(256), 0, stream>>>(kvbuf, ksbuf);
  lin_pass3<<<dim3(gB*gH*gNC), dim3(256), 0, stream>>>(q_r, k_r, vt, kvbuf, ksbuf, olocal, hbf);

  gemm256<0><<<dim3(32*8), dim3(512), 0, stream>>>(hbf, wob, (void*)out, 8192, 2048, 2048);
}

// Round 16
// 315.992 us; speedup vs baseline: 1.1922x; 1.0401x over previous
//
#include <hip/hip_runtime.h>

// ---------------- problem constants ----------------
#define gB 2
#define gS 4096
#define gH 32
#define gKVH 8
#define gHID 2048
#define gNC 32            // S / CHK
#define gBS (gB*gS)       // 8192
// D = 64, WIN = 256, CHK = 128, NREP = 4 are hard-coded below.

using bf16x8 = __attribute__((ext_vector_type(8))) short;
using f32x4  = __attribute__((ext_vector_type(4))) float;

__device__ __forceinline__ float bf2f(unsigned short u){
  return __uint_as_float(((unsigned)u) << 16);
}
__device__ __forceinline__ unsigned short f2bf(float f){
  unsigned u = __float_as_uint(f);
  u = (u + 0x7fffu + ((u >> 16) & 1u)) >> 16;   // RNE
  return (unsigned short)u;
}
__device__ __forceinline__ float phi_f(float x){ return x > 0.f ? x + 1.f : __expf(x); } // elu(x)+1

__device__ __forceinline__ void unpack8(uint4 v, unsigned short* o){
  o[0]=(unsigned short)(v.x&0xffffu); o[1]=(unsigned short)(v.x>>16);
  o[2]=(unsigned short)(v.y&0xffffu); o[3]=(unsigned short)(v.y>>16);
  o[4]=(unsigned short)(v.z&0xffffu); o[5]=(unsigned short)(v.z>>16);
  o[6]=(unsigned short)(v.w&0xffffu); o[7]=(unsigned short)(v.w>>16);
}
__device__ __forceinline__ uint4 pack8(const unsigned short* s){
  uint4 v;
  v.x = (unsigned)s[0] | ((unsigned)s[1]<<16);
  v.y = (unsigned)s[2] | ((unsigned)s[3]<<16);
  v.z = (unsigned)s[4] | ((unsigned)s[5]<<16);
  v.w = (unsigned)s[6] | ((unsigned)s[7]<<16);
  return v;
}

// async global->LDS, 16B per lane; LDS dest = wave-uniform base + lane*16
typedef const __attribute__((address_space(1))) void* gas_ptr;
typedef __attribute__((address_space(3))) void* las_ptr;
__device__ __forceinline__ void gload16(const void* g, void* l){
  __builtin_amdgcn_global_load_lds((gas_ptr)g, (las_ptr)l, 16, 0, 0);
}

// ---------------- fused f32 -> bf16 convert (hidden + Wq + Wk + Wv + Wo, 1 launch) ----------------
__global__ void cvt_all(const float* __restrict__ hidden, const float* __restrict__ Wq,
                        const float* __restrict__ Wk, const float* __restrict__ Wv,
                        const float* __restrict__ Wo, unsigned short* __restrict__ hbf,
                        unsigned short* __restrict__ wqkv, unsigned short* __restrict__ wob)
{
  const long HG = (long)gBS*gHID/4;        // 4,194,304 groups of 4 floats
  const long QG = 1048576, KG = 262144, VG = 262144, OG = 1048576;
  const long total = HG + QG + KG + VG + OG;
  long stride = (long)gridDim.x * blockDim.x;
  for (long i = (long)blockIdx.x*blockDim.x + threadIdx.x; i < total; i += stride){
    const float* src; unsigned short* dst; long off;
    if (i < HG)                { src = hidden; dst = hbf;                          off = i; }
    else if (i < HG+QG)        { src = Wq;     dst = wqkv;                         off = i - HG; }
    else if (i < HG+QG+KG)     { src = Wk;     dst = wqkv + (size_t)2048*gHID;     off = i - HG - QG; }
    else if (i < HG+QG+KG+VG)  { src = Wv;     dst = wqkv + (size_t)2560*gHID;     off = i - HG - QG - KG; }
    else                       { src = Wo;     dst = wob;                          off = i - HG - QG - KG - VG; }
    float4 v = *(const float4*)(src + off*4);
    ushort4 o;
    o.x = f2bf(v.x); o.y = f2bf(v.y); o.z = f2bf(v.z); o.w = f2bf(v.w);
    *(ushort4*)(dst + off*4) = o;
  }
}

// ---------------- QKV GEMM 128x256, BK=64, 2-buffer, 1 barrier/K-tile ----------------
__global__ __launch_bounds__(512, 2) void gemm_qkv(const unsigned short* __restrict__ A,
                                                   const unsigned short* __restrict__ Bm,
                                                   const float* __restrict__ cosb,
                                                   const float* __restrict__ sinb,
                                                   unsigned short* __restrict__ q_r,
                                                   unsigned short* __restrict__ k_r,
                                                   unsigned short* __restrict__ vproj)
{
  const int Kdim = 2048;
  __shared__ unsigned short Sh[2*24576];   // buf stride 49152 B: A (16 KB) + B (32 KB)
  int tid = threadIdx.x, lane = tid & 63, w = tid >> 6, lr = lane & 15, lg = lane >> 4;
  int wm = w >> 2, wn = w & 3;
  const int ntn = 12;                      // 3072/256
  int nwg = gridDim.x;
  int bid = (int)blockIdx.x;
  int swz = (bid & 7) * (nwg >> 3) + (bid >> 3);   // XCD-chunked (nwg % 8 == 0)
  long m0 = (long)(swz / ntn) * 128;
  long n0 = (long)(swz % ntn) * 256;
  const int NT = Kdim >> 6;                // 32

  f32x4 acc[4][4] = {};

  const char* gsrc[6]; unsigned ldst[6];
  #pragma unroll
  for (int i = 0; i < 2; ++i){             // A: 1024 chunks (128 rows x 8)
    int c = w*64 + lane + i*512;
    int row = c >> 3, g = c & 7;
    int colb = (g ^ (row & 7)) << 4;
    gsrc[i] = (const char*)A + ((m0 + row) * (long)Kdim)*2 + colb;
    ldst[i] = (unsigned)((w*64 + i*512)*16);
  }
  #pragma unroll
  for (int i = 0; i < 4; ++i){             // B: 2048 chunks (256 rows x 8)
    int c = w*64 + lane + i*512;
    int row = c >> 3, g = c & 7;
    int colb = (g ^ (row & 7)) << 4;
    gsrc[2+i] = (const char*)Bm + ((n0 + row) * (long)Kdim)*2 + colb;
    ldst[2+i] = (unsigned)(16384 + (w*64 + i*512)*16);
  }
  auto stage = [&](int t){
    int sb = (t & 1) * 49152;              // bytes
    long kb = (long)t << 7;                // t*128 bytes
    #pragma unroll
    for (int i = 0; i < 6; ++i)
      gload16(gsrc[i] + kb, (char*)Sh + sb + ldst[i]);
  };

  stage(0);
  for (int t = 0; t < NT; ++t){
    asm volatile("s_waitcnt vmcnt(0)" ::: "memory");
    __builtin_amdgcn_s_barrier();
    if (t + 1 < NT) stage(t + 1);
    int sb = (t & 1) * 24576;              // shorts
    #pragma unroll
    for (int kk = 0; kk < 2; ++kk){
      bf16x8 af[4], bfr[4];
      #pragma unroll
      for (int m = 0; m < 4; ++m){
        int row = wm*64 + m*16 + lr;
        af[m] = *(const bf16x8*)&Sh[sb + row*64 + (((kk*4 + lg) ^ (row & 7)) << 3)];
      }
      #pragma unroll
      for (int n = 0; n < 4; ++n){
        int row = wn*64 + n*16 + lr;
        bfr[n] = *(const bf16x8*)&Sh[sb + 8192 + row*64 + (((kk*4 + lg) ^ (row & 7)) << 3)];
      }
      __builtin_amdgcn_s_setprio(1);
      #pragma unroll
      for (int m = 0; m < 4; ++m)
        #pragma unroll
        for (int n = 0; n < 4; ++n)
          acc[m][n] = __builtin_amdgcn_mfma_f32_16x16x32_bf16(af[m], bfr[n], acc[m][n], 0, 0, 0);
      __builtin_amdgcn_s_setprio(0);
    }
  }

  // ---- fused epilogue. C/D layout: col = lane&15, row = 4*(lane>>4) + reg ----
  long colbase = n0 + wn*64;                 // 64-aligned; block section-uniform
  if (colbase < 2048){
    int head = (int)(colbase >> 6);
    #pragma unroll
    for (int m = 0; m < 4; ++m)
      #pragma unroll
      for (int r = 0; r < 4; ++r){
        long srow = m0 + wm*64 + m*16 + 4*lg + r;   // = b*gS + s
        int b = (int)(srow >> 12), s = (int)(srow & 4095);
        const float* cp = cosb + srow*64;
        const float* sp = sinb + srow*64;
        unsigned short* op = q_r + ((size_t)(b*gH + head)*gS + s)*64;
        #pragma unroll
        for (int n = 0; n < 2; ++n){
          int d = n*16 + lr;
          float x1 = acc[m][n][r], x2 = acc[m][n+2][r];
          op[d]      = f2bf(x1*cp[d]    - x2*sp[d]);
          op[d+32]   = f2bf(x2*cp[d+32] + x1*sp[d+32]);
        }
      }
  } else if (colbase < 2560){
    int head = (int)(colbase >> 6) - 32;
    #pragma unroll
    for (int m = 0; m < 4; ++m)
      #pragma unroll
      for (int r = 0; r < 4; ++r){
        long srow = m0 + wm*64 + m*16 + 4*lg + r;
        int b = (int)(srow >> 12), s = (int)(srow & 4095);
        const float* cp = cosb + srow*64;
        const float* sp = sinb + srow*64;
        unsigned short* op = k_r + ((size_t)(b*gKVH + head)*gS + s)*64;
        #pragma unroll
        for (int n = 0; n < 2; ++n){
          int d = n*16 + lr;
          float x1 = acc[m][n][r], x2 = acc[m][n+2][r];
          op[d]      = f2bf(x1*cp[d]    - x2*sp[d]);
          op[d+32]   = f2bf(x2*cp[d+32] + x1*sp[d+32]);
        }
      }
  } else {
    #pragma unroll
    for (int m = 0; m < 4; ++m)
      #pragma unroll
      for (int r = 0; r < 4; ++r){
        long srow = m0 + wm*64 + m*16 + 4*lg + r;
        unsigned short* op = vproj + (size_t)srow*512 + (colbase - 2560);
        #pragma unroll
        for (int n = 0; n < 4; ++n)
          op[n*16 + lr] = f2bf(acc[m][n][r]);
      }
  }
}

// ---------------- GEMM 256x256, BK=64, 2-buffer, 1 barrier/K-tile (Wo) ----------------
template<int OUT_BF16>
__global__ __launch_bounds__(512, 2) void gemm256(const unsigned short* __restrict__ A,
                                                  const unsigned short* __restrict__ Bm,
                                                  void* __restrict__ Cout,
                                                  int Mdim, int Ndim, int Kdim)
{
  __shared__ unsigned short Sh[2*32768];
  int tid = threadIdx.x, lane = tid & 63, w = tid >> 6, lr = lane & 15, lg = lane >> 4;
  int wm = w >> 2, wn = w & 3;
  int ntn = Ndim >> 8;
  int nwg = gridDim.x;
  int bid = (int)blockIdx.x;
  int swz = (bid & 7) * (nwg >> 3) + (bid >> 3);
  long m0 = (long)(swz / ntn) * 256;
  long n0 = (long)(swz % ntn) * 256;
  int NT = Kdim >> 6;

  f32x4 acc[8][4] = {};

  const char* gsrc[8]; unsigned ldst[8];
  #pragma unroll
  for (int i = 0; i < 4; ++i){
    int c = w*64 + lane + i*512;
    int row = c >> 3, g = c & 7;
    int colb = (g ^ (row & 7)) << 4;
    gsrc[i]   = (const char*)A  + ((m0 + row) * (long)Kdim)*2 + colb;
    ldst[i]   = (unsigned)((w*64 + i*512)*16);
    gsrc[4+i] = (const char*)Bm + ((n0 + row) * (long)Kdim)*2 + colb;
    ldst[4+i] = (unsigned)(32768 + (w*64 + i*512)*16);
  }
  auto stage = [&](int t){
    int sb = (t & 1) * 65536;
    long kb = (long)t << 7;
    #pragma unroll
    for (int i = 0; i < 8; ++i)
      gload16(gsrc[i] + kb, (char*)Sh + sb + ldst[i]);
  };

  stage(0);
  for (int t = 0; t < NT; ++t){
    asm volatile("s_waitcnt vmcnt(0)" ::: "memory");
    __builtin_amdgcn_s_barrier();
    if (t + 1 < NT) stage(t + 1);
    int sb = (t & 1) * 32768;
    #pragma unroll
    for (int kk = 0; kk < 2; ++kk){
      bf16x8 af[8], bfr[4];
      #pragma unroll
      for (int m = 0; m < 8; ++m){
        int row = wm*128 + m*16 + lr;
        af[m] = *(const bf16x8*)&Sh[sb + row*64 + (((kk*4 + lg) ^ (row & 7)) << 3)];
      }
      #pragma unroll
      for (int n = 0; n < 4; ++n){
        int row = wn*64 + n*16 + lr;
        bfr[n] = *(const bf16x8*)&Sh[sb + 16384 + row*64 + (((kk*4 + lg) ^ (row & 7)) << 3)];
      }
      __builtin_amdgcn_s_setprio(1);
      #pragma unroll
      for (int m = 0; m < 8; ++m)
        #pragma unroll
        for (int n = 0; n < 4; ++n)
          acc[m][n] = __builtin_amdgcn_mfma_f32_16x16x32_bf16(af[m], bfr[n], acc[m][n], 0, 0, 0);
      __builtin_amdgcn_s_setprio(0);
    }
  }

  #pragma unroll
  for (int m = 0; m < 8; ++m)
    #pragma unroll
    for (int n = 0; n < 4; ++n)
      #pragma unroll
      for (int r = 0; r < 4; ++r){
        long row = m0 + wm*128 + m*16 + 4*lg + r;
        long col = n0 + wn*64 + n*16 + lr;
        float v = acc[m][n][r];
        if (OUT_BF16) ((unsigned short*)Cout)[row*Ndim + col] = f2bf(v);
        else          ((float*)Cout)[row*Ndim + col] = v;
      }
}

// ---------------- fused transposes: k_r -> ktr (mode0) and vproj -> vt (mode1) ----------------
__global__ __launch_bounds__(256) void transpose2(const unsigned short* __restrict__ k_r,
                                                  unsigned short* __restrict__ ktr,
                                                  const unsigned short* __restrict__ vproj,
                                                  unsigned short* __restrict__ vt)
{
  __shared__ unsigned short T[64*72];
  int bid = blockIdx.x;
  int mode = bid >> 10; bid &= 1023;
  int st = bid & 63; int kvh = (bid >> 6) & 7; int b = bid >> 9;
  int s0 = st*64;
  int tid = threadIdx.x;
  const unsigned short* ip;
  unsigned short* out;
  size_t tokstr;
  if (mode == 0){ ip = k_r + ((size_t)(b*gKVH+kvh)*gS + s0)*64;      out = ktr; tokstr = 64; }
  else          { ip = vproj + (size_t)(b*gS+s0)*512 + kvh*64;       out = vt;  tokstr = 512; }
  #pragma unroll
  for (int i = 0; i < 2; ++i){
    int cc = tid + 256*i; int sl = cc >> 3, ch = cc & 7;
    *(uint4*)&T[sl*72 + ch*8] = *(const uint4*)&ip[(size_t)sl*tokstr + ch*8];
  }
  __syncthreads();
  unsigned short* op = out + ((size_t)(b*gKVH+kvh)*64)*gS;
  #pragma unroll
  for (int i = 0; i < 2; ++i){
    int cc = tid + 256*i; int d = cc >> 3, ch = cc & 7;
    unsigned short t[8];
    #pragma unroll
    for (int u = 0; u < 8; ++u) t[u] = T[(ch*8+u)*72 + d];
    *(uint4*)&op[(size_t)d*gS + s0 + ch*8] = pack8(t);
  }
}

// ---------------- FUSED attention: local sliding-window + linear pass3 + combine ----------------
// Phase L: no-max-softmax local attention (6 K-tiles, dbuf). At loop end Ks/VTs
// hold keys [q0,q0+128) == this chunk's intra K/V in the exact layouts lin needs.
// Phase T: pq=phi(Qs)->Pq area; pk=phi(Ks) in place.  Phase I: intra QK^T/mask/
// PV per 64-key half (Ph reuses dead Qs area; wave-private rows).  Phase S: SpT
// (Sprev d-major) overwrites Qs area; inter MFMA; den z-part.  Registers combine
// 0.5*local/psum + 0.5*lin/den -> hout. Writes hout only (olocal eliminated).
__global__ __launch_bounds__(512, 2) void attn_fused(const unsigned short* __restrict__ q_r,
                                                     const unsigned short* __restrict__ k_r,
                                                     const unsigned short* __restrict__ vt,
                                                     const float* __restrict__ Sprev,
                                                     const float* __restrict__ zprev,
                                                     unsigned short* __restrict__ hout)
{
  __shared__ unsigned short QsPh[128*72];   // raw Q -> Ph -> SpT
  __shared__ unsigned short Ks[2][64*72];   // K tiles -> phi(K) halves
  __shared__ unsigned short VTs[2][64*72];  // V^T tiles (d-major rows)
  __shared__ unsigned short Pq[128*72];     // local P staging -> phi(Q)
  __shared__ float zp[64];
  int bid = blockIdx.x;
  int qt = bid & 31; int h = (bid >> 5) & 31; int b = bid >> 10;
  int kvh = h >> 2;
  int q0 = qt*128;
  int tid = threadIdx.x, lane = tid & 63, w = tid >> 6, lr = lane & 15, lg = lane >> 4;
  const unsigned short* qp = q_r + ((size_t)(b*gH  +h  )*gS + q0)*64;
  const unsigned short* kp = k_r + ((size_t)(b*gKVH+kvh)*gS)*64;
  const unsigned short* vp = vt  + ((size_t)(b*gKVH+kvh)*64)*gS;   // rows d, stride S
  const float* Sp  = Sprev + ((size_t)((b*gKVH+kvh)*gNC + qt))*4096;
  const float* zpg = zprev + ((size_t)((b*gKVH+kvh)*gNC + qt))*64;

  // ---- Phase L: local attention ----
  #pragma unroll
  for (int i = 0; i < 2; ++i){
    int cc = tid + 512*i; int row = cc >> 3, ch = cc & 7;
    *(uint4*)&QsPh[row*72 + ch*8] = *(const uint4*)&qp[row*64 + ch*8];
  }

  int kt0 = (q0 >= 256) ? 0 : ((256 - q0) >> 6);
  int krow = tid >> 3, kch = tid & 7;       // 64 rows x 8 chunks = 512 threads
  uint4 kreg, vreg;
  {
    int kb = q0 - 256 + kt0*64;
    kreg = *(const uint4*)&kp[(size_t)(kb+krow)*64 + kch*8];
    vreg = *(const uint4*)&vp[(size_t)krow*gS + kb + kch*8];
    *(uint4*)&Ks[0][krow*72 + kch*8]  = kreg;
    *(uint4*)&VTs[0][krow*72 + kch*8] = vreg;
  }

  float psum[4] = {0.f, 0.f, 0.f, 0.f};
  f32x4 accO[4] = {};
  int wq = w*16;

  for (int kt = kt0; kt < 6; ++kt){
    int cur = (kt - kt0) & 1;
    __syncthreads();
    bool more = (kt + 1 < 6);
    if (more){
      int kb2 = q0 - 256 + (kt+1)*64;
      kreg = *(const uint4*)&kp[(size_t)(kb2+krow)*64 + kch*8];
      vreg = *(const uint4*)&vp[(size_t)krow*gS + kb2 + kch*8];
    }

    f32x4 sc[4] = {};
    #pragma unroll
    for (int kk = 0; kk < 64; kk += 32){
      bf16x8 aq = *(const bf16x8*)&QsPh[(wq+lr)*72 + kk + 8*lg];
      #pragma unroll
      for (int f = 0; f < 4; ++f){
        bf16x8 bk = *(const bf16x8*)&Ks[cur][(f*16+lr)*72 + kk + 8*lg];
        sc[f] = __builtin_amdgcn_mfma_f32_16x16x32_bf16(aq, bk, sc[f], 0, 0, 0);
      }
    }
    #pragma unroll
    for (int f = 0; f < 4; ++f)
      #pragma unroll
      for (int r = 0; r < 4; ++r){
        int i = wq + 4*lg + r;               // local query row (0..127)
        int j = kt*64 + f*16 + lr;           // window column (0..383)
        bool keep = (j > i) && (j <= i + 256);
        float e = __expf(sc[f][r] * 0.125f);
        float p = keep ? e : 0.f;
        psum[r] += p;
        Pq[w*1152 + (4*lg + r)*72 + f*16 + lr] = f2bf(p);
      }
    // Pq write->read is same-wave LDS (in-order DS pipe) — no barrier needed.
    #pragma unroll
    for (int kk = 0; kk < 64; kk += 32){
      bf16x8 ap = *(const bf16x8*)&Pq[w*1152 + lr*72 + kk + 8*lg];
      #pragma unroll
      for (int dt = 0; dt < 4; ++dt){
        bf16x8 bv = *(const bf16x8*)&VTs[cur][(dt*16+lr)*72 + kk + 8*lg];
        accO[dt] = __builtin_amdgcn_mfma_f32_16x16x32_bf16(ap, bv, accO[dt], 0, 0, 0);
      }
    }
    if (more){
      *(uint4*)&Ks[cur^1][krow*72 + kch*8]  = kreg;
      *(uint4*)&VTs[cur^1][krow*72 + kch*8] = vreg;
    }
  }
  // normalize local into registers: accO = 0.5 * local_out
  #pragma unroll
  for (int off = 1; off < 16; off <<= 1)
    #pragma unroll
    for (int r = 0; r < 4; ++r) psum[r] += __shfl_xor(psum[r], off);
  #pragma unroll
  for (int r = 0; r < 4; ++r){
    float inv = 0.5f / psum[r];
    #pragma unroll
    for (int dt = 0; dt < 4; ++dt) accO[dt][r] *= inv;
  }

  // ---- Phase T: pq = phi(Qs) -> Pq; pk = phi(Ks) in place ----
  __syncthreads();   // all local QK/PV reads of Ks/VTs/Pq/QsPh done
  {
    int row = tid >> 2, c0 = (tid & 3) * 16;   // 128 rows x 4 col-groups
    #pragma unroll
    for (int hlf = 0; hlf < 2; ++hlf){
      unsigned short t[8];
      unpack8(*(const uint4*)&QsPh[row*72 + c0 + hlf*8], t);
      #pragma unroll
      for (int u = 0; u < 8; ++u) t[u] = f2bf(phi_f(bf2f(t[u])));
      *(uint4*)&Pq[row*72 + c0 + hlf*8] = pack8(t);
    }
    #pragma unroll
    for (int bf = 0; bf < 2; ++bf){
      unsigned short t[8];
      unpack8(*(const uint4*)&Ks[bf][krow*72 + kch*8], t);
      #pragma unroll
      for (int u = 0; u < 8; ++u) t[u] = f2bf(phi_f(bf2f(t[u])));
      *(uint4*)&Ks[bf][krow*72 + kch*8] = pack8(t);
    }
  }
  __syncthreads();

  // ---- Phase I: intra-chunk linear attention (2 halves of 64 keys) ----
  float den[4] = {};
  f32x4 accL[4] = {};
  #pragma unroll
  for (int kh = 0; kh < 2; ++kh){
    int kb = (kt0 + kh) & 1;                 // buffer holding keys [q0+kh*64, ...)
    f32x4 sc[4] = {};
    #pragma unroll
    for (int kk = 0; kk < 64; kk += 32){
      bf16x8 a = *(const bf16x8*)&Pq[(wq+lr)*72 + kk + 8*lg];
      #pragma unroll
      for (int ct = 0; ct < 4; ++ct){
        bf16x8 bk = *(const bf16x8*)&Ks[kb][(16*ct+lr)*72 + kk + 8*lg];
        sc[ct] = __builtin_amdgcn_mfma_f32_16x16x32_bf16(a, bk, sc[ct], 0, 0, 0);
      }
    }
    #pragma unroll
    for (int ct = 0; ct < 4; ++ct)
      #pragma unroll
      for (int r = 0; r < 4; ++r){
        int qrow = wq + 4*lg + r;
        int kro  = kh*64 + 16*ct + lr;
        float sv = (kro <= qrow) ? sc[ct][r] : 0.f;   // tril incl. diagonal
        den[r] += sv;
        QsPh[qrow*72 + 16*ct + lr] = f2bf(sv);        // Ph: wave-private rows
      }
    #pragma unroll
    for (int kk = 0; kk < 64; kk += 32){
      bf16x8 ap = *(const bf16x8*)&QsPh[(wq+lr)*72 + kk + 8*lg];
      #pragma unroll
      for (int et = 0; et < 4; ++et){
        bf16x8 bv = *(const bf16x8*)&VTs[kb][(16*et+lr)*72 + kk + 8*lg];
        accL[et] = __builtin_amdgcn_mfma_f32_16x16x32_bf16(ap, bv, accL[et], 0, 0, 0);
      }
    }
  }

  // ---- Phase S: inter-chunk via Sprev (SpT overwrites Qs/Ph area) ----
  __syncthreads();   // all waves done with QsPh as Ph
  #pragma unroll
  for (int i = 0; i < 8; ++i){
    int f = tid + 512*i; int d = f >> 6, e = f & 63;  // Sp is d-major [d][e]
    QsPh[e*72 + d] = f2bf(Sp[f]);                     // SpT rows e, cols d
  }
  if (tid < 64) zp[tid] = zpg[tid];
  __syncthreads();
  #pragma unroll
  for (int kk = 0; kk < 64; kk += 32){
    bf16x8 a = *(const bf16x8*)&Pq[(wq+lr)*72 + kk + 8*lg];
    #pragma unroll
    for (int et = 0; et < 4; ++et){
      bf16x8 bs = *(const bf16x8*)&QsPh[(16*et+lr)*72 + kk + 8*lg];
      accL[et] = __builtin_amdgcn_mfma_f32_16x16x32_bf16(a, bs, accL[et], 0, 0, 0);
    }
  }
  #pragma unroll
  for (int r = 0; r < 4; ++r){
    int qrow = wq + 4*lg + r;
    float part = 0.f;
    #pragma unroll
    for (int u = 0; u < 4; ++u){
      int d = 4*lr + u;
      part += bf2f(Pq[qrow*72 + d]) * zp[d];
    }
    den[r] += part;
    #pragma unroll
    for (int off = 1; off < 16; off <<= 1)
      den[r] += __shfl_xor(den[r], off);
  }

  // ---- combine in registers and write ----
  #pragma unroll
  for (int dt = 0; dt < 4; ++dt)
    #pragma unroll
    for (int r = 0; r < 4; ++r){
      int s = q0 + wq + 4*lg + r;
      int d = dt*16 + lr;
      float val = accO[dt][r] + 0.5f * accL[dt][r] / (den[r] + 1e-6f);
      hout[((size_t)(b*gS+s)*gH + h)*64 + d] = f2bf(val);
    }
}

// ---------------- linear attention pass 1 ----------------
__global__ __launch_bounds__(256) void lin_pass1(const unsigned short* __restrict__ ktr,
                                                 const unsigned short* __restrict__ vt,
                                                 float* __restrict__ kvbuf, float* __restrict__ ksbuf)
{
  __shared__ unsigned short pkT[64*136];
  __shared__ unsigned short vT[64*136];
  int bid = blockIdx.x;
  int c = bid & 31; int kvh = (bid >> 5) & 7; int b = bid >> 8;
  int tid = threadIdx.x, lane = tid & 63, w = tid >> 6, lr = lane & 15, lg = lane >> 4;
  int s0 = c*128;
  const unsigned short* kp = ktr + ((size_t)(b*gKVH+kvh)*64)*gS;
  const unsigned short* vp = vt  + ((size_t)(b*gKVH+kvh)*64)*gS;
  #pragma unroll
  for (int i = 0; i < 4; ++i){
    int cc = tid + 256*i; int d = cc >> 4, ch = cc & 15;
    unsigned short t[8]; unpack8(*(const uint4*)&kp[(size_t)d*gS + s0 + ch*8], t);
    #pragma unroll
    for (int u = 0; u < 8; ++u) t[u] = f2bf(phi_f(bf2f(t[u])));
    *(uint4*)&pkT[d*136 + ch*8] = pack8(t);
    *(uint4*)&vT[d*136 + ch*8]  = *(const uint4*)&vp[(size_t)d*gS + s0 + ch*8];
  }
  __syncthreads();
  f32x4 acc[4] = {};
  #pragma unroll
  for (int kk = 0; kk < 128; kk += 32){
    bf16x8 a = *(const bf16x8*)&pkT[(16*w+lr)*136 + kk + 8*lg];
    #pragma unroll
    for (int et = 0; et < 4; ++et){
      bf16x8 bv = *(const bf16x8*)&vT[(16*et+lr)*136 + kk + 8*lg];
      acc[et] = __builtin_amdgcn_mfma_f32_16x16x32_bf16(a, bv, acc[et], 0, 0, 0);
    }
  }
  size_t base = (size_t)((b*gKVH+kvh)*gNC + c);
  float* kvp = kvbuf + base*4096;
  #pragma unroll
  for (int et = 0; et < 4; ++et)
    #pragma unroll
    for (int r = 0; r < 4; ++r)
      kvp[(16*w + 4*lg + r)*64 + 16*et + lr] = acc[et][r];   // d-major [d][e]
  if (tid < 64){
    float sum = 0.f;
    for (int k = 0; k < 128; ++k) sum += bf2f(pkT[tid*136 + k]);
    ksbuf[base*64 + tid] = sum;
  }
}

// ---------------- linear attention pass 2: in-place exclusive scan (d-major kept) ----------------
__global__ void lin_pass2(float* __restrict__ kvbuf, float* __restrict__ ksbuf){
  int t = blockIdx.x*256 + threadIdx.x;
  const int per = 4096 + 64;
  if (t >= gB*gKVH*per) return;
  int bh = t / per; int e = t % per;
  if (e < 4096){
    float* p = kvbuf + (size_t)bh*gNC*4096 + e;   // coalesced read AND write
    float acc = 0.f;
    for (int cix = 0; cix < gNC; ++cix){ float v = p[(size_t)cix*4096]; p[(size_t)cix*4096] = acc; acc += v; }
  } else {
    float* p = ksbuf + (size_t)bh*gNC*64 + (e - 4096);
    float acc = 0.f;
    for (int cix = 0; cix < gNC; ++cix){ float v = p[cix*64]; p[cix*64] = acc; acc += v; }
  }
}

// ---------------- host launch ----------------
extern "C" void kernel_launch(void* const* d_in, const int* in_sizes, int n_in,
                              void* d_out, int out_size, void* d_ws, size_t ws_size,
                              hipStream_t stream)
{
  const float* hidden = (const float*)d_in[0];
  const float* cosb   = (const float*)d_in[1];
  const float* sinb   = (const float*)d_in[2];
  const float* Wq     = (const float*)d_in[3];
  const float* Wk     = (const float*)d_in[4];
  const float* Wv     = (const float*)d_in[5];
  const float* Wo     = (const float*)d_in[6];
  float* out = (float*)d_out;

  char* ws = (char*)d_ws;
  size_t off = 0;
  auto alloc = [&](size_t bytes)->void*{
    void* p = ws + off; off += (bytes + 255) & ~(size_t)255; return p;
  };
  unsigned short* hbf    = (unsigned short*)alloc((size_t)gBS*gHID*2);   // hidden bf16; reused as hybrid bf16
  unsigned short* wqkv   = (unsigned short*)alloc((size_t)3072*gHID*2);  // [Wq;Wk;Wv]
  unsigned short* wob    = (unsigned short*)alloc((size_t)gHID*gHID*2);
  unsigned short* vproj  = (unsigned short*)alloc((size_t)gBS*512*2);    // (B,S,KVH*64)
  unsigned short* q_r    = (unsigned short*)alloc((size_t)gBS*gHID*2);   // (B,H,S,64)
  unsigned short* k_r    = (unsigned short*)alloc((size_t)gBS*512*2);    // (B,KVH,S,64)
  unsigned short* ktr    = (unsigned short*)alloc((size_t)gBS*512*2);    // (B,KVH,64,S)
  unsigned short* vt     = (unsigned short*)alloc((size_t)gBS*512*2);    // (B,KVH,64,S)
  float* kvbuf           = (float*)alloc((size_t)gB*gKVH*gNC*4096*4);    // d-major; scanned in place
  float* ksbuf           = (float*)alloc((size_t)gB*gKVH*gNC*64*4);

  // fused convert: hidden + Wq + Wk + Wv + Wo in one launch
  cvt_all<<<dim3(2048), dim3(256), 0, stream>>>(hidden, Wq, Wk, Wv, Wo, hbf, wqkv, wob);

  // fused QKV projection + RoPE + layout (q_r, k_r, vproj)
  gemm_qkv<<<dim3(64*12), dim3(512), 0, stream>>>(hbf, wqkv, cosb, sinb, q_r, k_r, vproj);

  transpose2<<<dim3(2048), dim3(256), 0, stream>>>(k_r, ktr, vproj, vt);

  lin_pass1<<<dim3(gB*gKVH*gNC), dim3(256), 0, stream>>>(ktr, vt, kvbuf, ksbuf);
  lin_pass2<<<dim3((gB*gKVH*(4096+64) + 255)/256), dim3(256), 0, stream>>>(kvbuf, ksbuf);

  // fused local-window + linear-pass3 + combine -> hbf (hybrid bf16)
  attn_fused<<<dim3(gB*gH*32), dim3(512), 0, stream>>>(q_r, k_r, vt, kvbuf, ksbuf, hbf);

  gemm256<0><<<dim3(32*8), dim3(512), 0, stream>>>(hbf, wob, (void*)out, 8192, 2048, 2048);
}